// Round 14
// baseline (2086.470 us; speedup 1.0000x reference)
//
#include <hip/hip_runtime.h>
#include <stdint.h>
#include <stdio.h>

typedef __attribute__((ext_vector_type(8))) short short8;
typedef __attribute__((ext_vector_type(4))) float f32x4;
typedef __attribute__((ext_vector_type(2))) float f32x2;
typedef __attribute__((ext_vector_type(4))) unsigned int u32x4;
typedef __attribute__((ext_vector_type(4))) unsigned short u16x4;

#define DEV static __device__ __forceinline__

DEV unsigned short f2bf(float f){
  unsigned u = __float_as_uint(f);
  u += 0x7FFFu + ((u >> 16) & 1u);          // RNE
  return (unsigned short)(u >> 16);
}
DEV float bf2f(unsigned short h){ return __uint_as_float(((unsigned)h) << 16); }

// ---------------------------------------------------------------------------
// x (8,96,256,256) f32  ->  xt (8,260,260,128) bf16 channels-last with halo=2
// ---------------------------------------------------------------------------
__global__ __launch_bounds__(256) void k_xt(const float* __restrict__ x,
                                            unsigned short* __restrict__ xt){
  int bid = blockIdx.x;                 // 8*256*4
  int wq = bid & 3, h = (bid >> 2) & 255, b = bid >> 10;
  int w0 = wq * 64;
  __shared__ unsigned short s[64 * 104];
  int t = threadIdx.x;
  int wl = t & 63, cq = t >> 6;         // cq 0..3
  const float* xp = x + ((size_t)b * 96 * 256 + h) * 256 + w0 + wl;
  #pragma unroll
  for (int i = 0; i < 24; ++i){
    int c = cq + i * 4;                 // 0..95
    s[wl * 104 + c] = f2bf(xp[(size_t)c * 65536]);
  }
  __syncthreads();
  unsigned short* dst = xt + (((size_t)b * 260 + h + 2) * 260 + (w0 + 2)) * 128;
  #pragma unroll
  for (int p = 0; p < 3; ++p){
    int i = t + p * 256;                // 0..767 = 64 w * 12 chunks
    int w = i / 12, ch = i % 12;
    u32x4 v = *(const u32x4*)&s[w * 104 + ch * 8];
    *(u32x4*)&dst[(size_t)w * 128 + ch * 8] = v;
  }
}

// ---------------------------------------------------------------------------
// weight repack (bf16):
//  A3  MFMA-fragment order for k_conv:
//      idx = (((((mt*25 + kh*5+kw)*3 + ics)*2 + mw)*4 + mf)*64 + lane)*8 + e
//      holds W[oc = mt*128+mw*64+mf*16+(lane&15)][ic = ics*32+(lane>>4)*8+e]
//  Aun [m=co*4+p*2+q][ci 0..767]    unpatch weights
//  Agr [side][m 0..191][k 0..95]    gru weights transposed
//  bun [96] f32 = r_un_b + c_un_b
// ---------------------------------------------------------------------------
__global__ __launch_bounds__(256) void k_pack(const float* __restrict__ rpw, const float* __restrict__ cpw,
    const float* __restrict__ runw, const float* __restrict__ cunw,
    const float* __restrict__ runb, const float* __restrict__ cunb,
    const float* __restrict__ rgw,  const float* __restrict__ cgw,
    unsigned short* __restrict__ A3, unsigned short* __restrict__ Aun,
    unsigned short* __restrict__ Agr, float* __restrict__ bun){
  int tid = blockIdx.x * 256 + threadIdx.x;
  const int NA3 = 768 * 2400, NUN = 384 * 768, NGR = 2 * 192 * 96;
  if (tid < NA3){
    int e = tid & 7, lane = (tid >> 3) & 63, mf = (tid >> 9) & 3, mw = (tid >> 11) & 1;
    int r = tid >> 12;
    int ics = r % 3, r2 = r / 3;
    int s = r2 % 25, mt = r2 / 25;
    int kh = s / 5, kw = s % 5;
    int oc = mt * 128 + mw * 64 + mf * 16 + (lane & 15);
    int ic = ics * 32 + (lane >> 4) * 8 + e;
    const float* W = oc < 384 ? rpw : cpw;
    int o = oc < 384 ? oc : oc - 384;
    A3[tid] = f2bf(W[(((size_t)o * 96 + ic) * 5 + kh) * 5 + kw]);
  } else if (tid < NA3 + NUN){
    int i = tid - NA3;
    int m = i / 768, ci = i % 768;
    int co = m >> 2, p = (m >> 1) & 1, q = m & 1;
    const float* W = ci < 384 ? runw : cunw;
    int c = ci < 384 ? ci : ci - 384;
    Aun[i] = f2bf(W[(((size_t)c * 96 + co) * 2 + p) * 2 + q]);
  } else if (tid < NA3 + NUN + NGR){
    int i = tid - NA3 - NUN;
    int side = i / 18432, r = i % 18432;
    int m = r / 96, k = r % 96;
    const float* W = side ? cgw : rgw;       // (96,192) row-major
    Agr[i] = f2bf(W[k * 192 + m]);
  } else if (tid < NA3 + NUN + NGR + 96){
    int co = tid - NA3 - NUN - NGR;
    bun[co] = runb[co] + cunb[co];
  }
}

// ---------------------------------------------------------------------------
// patch conv as implicit GEMM, v9 = v8 with LDS < 64KB (208B column pitch,
// NO swizzle needed: bank = (52*col + 4*ch) mod 32 self-spreads since col
// steps by 2 per lane -> 8*wl mod 32 covers banks).  B = 2r x 131c x 208B =
// 54496 B -> 2 blocks/CU (8 waves).  A from GLOBAL in fragment order (A3),
// batched 12-fragment load per slab; NO A barriers; 2 barriers per kh.
// Block 128oc x 128px (2 ho x 64 wo), 4 waves (2mw x 2nw), wave 64x64.
// ---------------------------------------------------------------------------
__global__ __launch_bounds__(256) void k_conv(const unsigned short* __restrict__ xt,
    const unsigned short* __restrict__ A3,
    const float* __restrict__ rpb, const float* __restrict__ cpb,
    unsigned short* __restrict__ cl){
  __shared__ char lds[54496];
  const int BPITCH = 27248;             // 131 cols * 208 B
  const int BITEMS = 3144;              // 2 rows * 131 cols * 12 ch
  int t = threadIdx.x, lane = t & 63;
  int wid = t >> 6, mw = wid >> 1, nw = wid & 1;
  int wl = lane & 15, cg = lane >> 4;
  int bid = blockIdx.x;                 // 6144 = 8 xcd * (128 pgrp * 6 m)
  int xcd = bid & 7, rr = bid >> 3;
  int mt = rr % 6, pgrp = rr / 6;
  int p = pgrp * 8 + xcd;               // pixel tile 0..1023
  int wq = p & 1, hq = (p >> 1) & 63, b = p >> 7;
  int ho0 = hq * 2, wo0 = wq * 64;
  int M0 = mt * 128;

  // per-lane A base (elements): fragment = A3[... + lane*8]
  const unsigned short* Abase = A3 + (size_t)mt * 307200 + mw * 2048 + lane * 8;

  f32x4 acc[4][4];
  #pragma unroll
  for (int i = 0; i < 4; ++i)
    #pragma unroll
    for (int j = 0; j < 4; ++j) acc[i][j] = (f32x4){0.f, 0.f, 0.f, 0.f};

  u32x4 bR[13];
  // ---- prologue: B(kh=0) ----
  #pragma unroll
  for (int it = 0; it < 13; ++it){
    int i = t + it * 256;
    if (i < BITEMS){
      int row = i / 1572, j = i % 1572, col = j / 12, ch = j % 12;
      bR[it] = *(const u32x4*)&xt[(((size_t)b * 260 + 2 * ho0 + 2 * row) * 260 + 2 * wo0 + col) * 128 + ch * 8];
    }
  }
  #pragma unroll
  for (int it = 0; it < 13; ++it){
    int i = t + it * 256;
    if (i < BITEMS){
      int row = i / 1572, j = i % 1572, col = j / 12, ch = j % 12;
      *(u32x4*)(lds + row * BPITCH + col * 208 + ch * 16) = bR[it];
    }
  }
  __syncthreads();

  for (int kh = 0; kh < 5; ++kh){
    #pragma unroll
    for (int kw = 0; kw < 5; ++kw){
      // issue next-kh B prefetch under compute
      if (kw == 4 && kh < 4){
        #pragma unroll
        for (int it = 0; it < 13; ++it){
          int i = t + it * 256;
          if (i < BITEMS){
            int row = i / 1572, j = i % 1572, col = j / 12, ch = j % 12;
            bR[it] = *(const u32x4*)&xt[(((size_t)b * 260 + 2 * ho0 + 2 * row + kh + 1) * 260 + 2 * wo0 + col) * 128 + ch * 8];
          }
        }
      }
      // ---- compute slab (kh,kw): batched A loads, 48 MFMA per wave ----
      const unsigned short* Asl = Abase + (size_t)(kh * 5 + kw) * 12288;
      short8 afx[12];
      #pragma unroll
      for (int q = 0; q < 12; ++q)
        afx[q] = *(const short8*)(Asl + (q >> 2) * 4096 + (q & 3) * 512);
      #pragma unroll
      for (int ics = 0; ics < 3; ++ics){
        short8 bfr[4];
        #pragma unroll
        for (int nf = 0; nf < 4; ++nf){
          int col = 32 * nf + 2 * wl + kw;
          bfr[nf] = *(const short8*)(lds + nw * BPITCH + col * 208 + (ics * 4 + cg) * 16);
        }
        #pragma unroll
        for (int mf = 0; mf < 4; ++mf)
          #pragma unroll
          for (int nf = 0; nf < 4; ++nf)
            acc[mf][nf] = __builtin_amdgcn_mfma_f32_16x16x32_bf16(afx[ics * 4 + mf], bfr[nf], acc[mf][nf], 0, 0, 0);
      }
    }
    if (kh < 4){
      __syncthreads();                  // all waves done reading B(kh)
      #pragma unroll
      for (int it = 0; it < 13; ++it){
        int i = t + it * 256;
        if (i < BITEMS){
          int row = i / 1572, j = i % 1572, col = j / 12, ch = j % 12;
          *(u32x4*)(lds + row * BPITCH + col * 208 + ch * 16) = bR[it];
        }
      }
      __syncthreads();                  // B(kh+1) visible
    }
  }
  // epilogue: bias, stash to LDS [128 px][128 oc] (swizzled), coop cl write
  __syncthreads();
  unsigned short* S = (unsigned short*)lds;
  #pragma unroll
  for (int mf = 0; mf < 4; ++mf)
    #pragma unroll
    for (int nf = 0; nf < 4; ++nf){
      int pxl = nw * 64 + nf * 16 + wl;
      int sw8 = (pxl & 7) << 3;
      #pragma unroll
      for (int j = 0; j < 4; ++j){
        int ocl = mw * 64 + mf * 16 + cg * 4 + j;
        int oc = M0 + ocl;
        float v = acc[mf][nf][j] + (oc < 384 ? rpb[oc] : cpb[oc - 384]);
        S[pxl * 128 + (ocl ^ sw8)] = f2bf(v);
      }
    }
  __syncthreads();
  #pragma unroll
  for (int it = 0; it < 8; ++it){
    int i = t + it * 256;               // 0..2047 = 128 px * 16 chunks
    int pxl = i >> 4, ch = i & 15;
    int chs = ch ^ (pxl & 7);
    int ho = ho0 + (pxl >> 6), wo = wo0 + (pxl & 63);
    u32x4 v = *(const u32x4*)&S[pxl * 128 + chs * 8];
    *(u32x4*)&cl[(((size_t)b * 128 + ho) * 128 + wo) * 768 + M0 + ch * 8] = v;
  }
}

// ---------------------------------------------------------------------------
// positional grouped conv 3x3, v2 (validated round 12).
// ---------------------------------------------------------------------------
__global__ __launch_bounds__(256) void k_pe(const unsigned short* __restrict__ cl,
    const float* __restrict__ rpew, const float* __restrict__ cpew,
    const float* __restrict__ rpeb, const float* __restrict__ cpeb,
    unsigned short* __restrict__ sum){
  __shared__ unsigned short si[340 * 52];  // [pix = r2*34+cc][ch pitch 52]
  __shared__ float sw[48 * 36];
  __shared__ float sb[48];
  int bid = blockIdx.x;                    // 8*16*16*4
  int wq = bid & 3, hq = (bid >> 2) & 15, slab = (bid >> 6) & 15, b = bid >> 10;
  int ch0 = slab * 48, hp0 = hq * 8, wp0 = wq * 32;
  int t = threadIdx.x;
  for (int i = t; i < 48 * 36; i += 256){
    int ocl = i / 36, r = i % 36;
    int oc = ch0 + ocl;
    const float* W = oc < 384 ? rpew : cpew;
    int o = oc < 384 ? oc : oc - 384;
    sw[i] = W[(size_t)o * 36 + r];
  }
  if (t < 48){
    int oc = ch0 + t;
    sb[t] = oc < 384 ? rpeb[oc] : cpeb[oc - 384];
  }
  for (int i = t; i < 340 * 24; i += 256){   // u32 = 2 ch at a time
    int pix = i / 24, c2 = i % 24;
    int r2 = pix / 34, cc = pix % 34;
    int hp = hp0 - 1 + r2, wp = wp0 - 1 + cc;
    unsigned v = 0;
    if (hp >= 0 && hp < 128 && wp >= 0 && wp < 128)
      v = *(const unsigned*)&cl[((size_t)b * 16384 + hp * 128 + wp) * 768 + ch0 + c2 * 2];
    *(unsigned*)&si[pix * 52 + c2 * 2] = v;
  }
  __syncthreads();
  int hpl = t >> 5, wpl = t & 31;
  unsigned int outp[24];
  #pragma unroll
  for (int g = 0; g < 12; ++g){
    float o0 = sb[g * 4], o1 = sb[g * 4 + 1], o2 = sb[g * 4 + 2], o3 = sb[g * 4 + 3];
    #pragma unroll
    for (int dh = 0; dh < 3; ++dh)
      #pragma unroll
      for (int dw = 0; dw < 3; ++dw){
        int pix = (hpl + dh) * 34 + (wpl + dw);
        u16x4 v = *(const u16x4*)&si[pix * 52 + g * 4];
        float x0 = bf2f(v[0]), x1 = bf2f(v[1]), x2 = bf2f(v[2]), x3 = bf2f(v[3]);
        int r = dh * 3 + dw;
        o0 = fmaf(sw[(g*4+0)*36 + 0*9 + r], x0, o0); o0 = fmaf(sw[(g*4+0)*36 + 1*9 + r], x1, o0);
        o0 = fmaf(sw[(g*4+0)*36 + 2*9 + r], x2, o0); o0 = fmaf(sw[(g*4+0)*36 + 3*9 + r], x3, o0);
        o1 = fmaf(sw[(g*4+1)*36 + 0*9 + r], x0, o1); o1 = fmaf(sw[(g*4+1)*36 + 1*9 + r], x1, o1);
        o1 = fmaf(sw[(g*4+1)*36 + 2*9 + r], x2, o1); o1 = fmaf(sw[(g*4+1)*36 + 3*9 + r], x3, o1);
        o2 = fmaf(sw[(g*4+2)*36 + 0*9 + r], x0, o2); o2 = fmaf(sw[(g*4+2)*36 + 1*9 + r], x1, o2);
        o2 = fmaf(sw[(g*4+2)*36 + 2*9 + r], x2, o2); o2 = fmaf(sw[(g*4+2)*36 + 3*9 + r], x3, o2);
        o3 = fmaf(sw[(g*4+3)*36 + 0*9 + r], x0, o3); o3 = fmaf(sw[(g*4+3)*36 + 1*9 + r], x1, o3);
        o3 = fmaf(sw[(g*4+3)*36 + 2*9 + r], x2, o3); o3 = fmaf(sw[(g*4+3)*36 + 3*9 + r], x3, o3);
      }
    outp[g * 2]     = (unsigned)f2bf(o0) | ((unsigned)f2bf(o1) << 16);
    outp[g * 2 + 1] = (unsigned)f2bf(o2) | ((unsigned)f2bf(o3) << 16);
  }
  size_t obase = (((size_t)b * 128 + hp0 + hpl) * 128 + wp0 + wpl) * 768 + ch0;
  #pragma unroll
  for (int c6 = 0; c6 < 6; ++c6){
    u32x4 v = { outp[c6 * 4], outp[c6 * 4 + 1], outp[c6 * 4 + 2], outp[c6 * 4 + 3] };
    *(u32x4*)&sum[obase + c6 * 8] = v;
  }
}

// ---------------------------------------------------------------------------
// FUSED hg-GEMM + minGRU scan (validated round 12).
// ---------------------------------------------------------------------------
__global__ __launch_bounds__(256) void k_gruf(const unsigned short* __restrict__ cl,
    const unsigned short* __restrict__ Agr, unsigned short* __restrict__ sum){
  __shared__ char lds[78848];
  const int AOFF = 0, BOFF2 = 39936, HOFF = 53248;
  int t = threadIdx.x, lane = t & 63, wid = t >> 6;
  int wl = lane & 15, cg = lane >> 4;
  int bid = blockIdx.x;
  int cb = bid & 7, head = (bid >> 3) & 3, b = (bid >> 5) & 7, side = bid >> 8;
  size_t clbase = ((size_t)b * 16384) * 768 + side * 384 + head * 96;
  for (int i = t; i < 2304; i += 256){
    int m = i / 12, c = i % 12;
    u32x4 v = *(const u32x4*)&Agr[((size_t)side * 192 + m) * 96 + c * 8];
    *(u32x4*)(lds + AOFF + m * 208 + c * 16) = v;
  }
  for (int i = t; i < 768; i += 256){
    int px = i / 12, c = i % 12;
    int s = px >> 4, xl = px & 15;
    int xg = cb * 16 + xl;
    int pxg = side ? (xg * 128 + s) : (s * 128 + xg);
    u32x4 v = *(const u32x4*)&cl[clbase + (size_t)pxg * 768 + c * 8];
    *(u32x4*)(lds + BOFF2 + px * 208 + c * 16) = v;
  }
  int s_chain = t & 15, s_dg = t >> 4;    // scan role: active if s_dg < 12
  float h[8];
  #pragma unroll
  for (int k = 0; k < 8; ++k) h[k] = 0.f;
  __syncthreads();

  for (int ch = 0; ch < 32; ++ch){
    int s0 = ch * 4;
    f32x4 acc[12];
    #pragma unroll
    for (int i = 0; i < 12; ++i) acc[i] = (f32x4){0.f, 0.f, 0.f, 0.f};
    #pragma unroll
    for (int ks = 0; ks < 3; ++ks){
      short8 bf = *(const short8*)(lds + BOFF2 + (wid * 16 + wl) * 208 + ks * 64 + cg * 16);
      #pragma unroll
      for (int mf = 0; mf < 12; ++mf){
        short8 af = *(const short8*)(lds + AOFF + (mf * 16 + wl) * 208 + ks * 64 + cg * 16);
        acc[mf] = __builtin_amdgcn_mfma_f32_16x16x32_bf16(af, bf, acc[mf], 0, 0, 0);
      }
    }
    {
      int px = wid * 16 + wl;
      #pragma unroll
      for (int mf = 0; mf < 12; ++mf){
        unsigned p0 = (unsigned)f2bf(acc[mf][0]) | ((unsigned)f2bf(acc[mf][1]) << 16);
        unsigned p1 = (unsigned)f2bf(acc[mf][2]) | ((unsigned)f2bf(acc[mf][3]) << 16);
        unsigned long long pp = (unsigned long long)p0 | ((unsigned long long)p1 << 32);
        *(unsigned long long*)(lds + HOFF + px * 400 + (mf * 16 + cg * 4) * 2) = pp;
      }
    }
    __syncthreads();
    if (s_dg < 12){
      #pragma unroll
      for (int s = 0; s < 4; ++s){
        int px = s * 16 + s_chain;
        short8 hid8 = *(const short8*)(lds + HOFF + px * 400 + s_dg * 16);
        short8 gat8 = *(const short8*)(lds + HOFF + px * 400 + 192 + s_dg * 16);
        int xg = cb * 16 + s_chain;
        int pxg = side ? (xg * 128 + (s0 + s)) : ((s0 + s) * 128 + xg);
        unsigned short* sp = (unsigned short*)&sum[clbase + (size_t)pxg * 768 + s_dg * 8];
        u32x4 sv = *(u32x4*)sp;
        unsigned short* svp = (unsigned short*)&sv;
        #pragma unroll
        for (int k = 0; k < 8; ++k){
          float hid = bf2f((unsigned short)hid8[k]);
          float gat = bf2f((unsigned short)gat8[k]);
          float z  = 1.f / (1.f + __expf(-gat));
          float th = hid >= 0.f ? hid + 0.5f : 1.f / (1.f + __expf(-hid));
          h[k] += z * (th - h[k]);
          svp[k] = f2bf(bf2f(svp[k]) + h[k]);
        }
        *(u32x4*)sp = sv;
      }
    }
    if (ch < 31){
      int sn = (ch + 1) * 4;
      for (int i = t; i < 768; i += 256){
        int px = i / 12, c = i % 12;
        int s = px >> 4, xl = px & 15;
        int xg = cb * 16 + xl;
        int pxg = side ? (xg * 128 + (sn + s)) : ((sn + s) * 128 + xg);
        u32x4 v = *(const u32x4*)&cl[clbase + (size_t)pxg * 768 + c * 8];
        *(u32x4*)(lds + BOFF2 + px * 208 + c * 16) = v;
      }
    }
    __syncthreads();
  }
}

// ---------------------------------------------------------------------------
// unpatch, v3 (validated round 13): XCD-grouped grid + paired f32x2 stores.
// ---------------------------------------------------------------------------
__global__ __launch_bounds__(256) void k_unpatch(const unsigned short* __restrict__ sum,
    const unsigned short* __restrict__ Aun, const float* __restrict__ bun,
    float* __restrict__ out){
  __shared__ char lds[53248];            // A [128][208B] | B [128][208B]
  int t = threadIdx.x, lane = t & 63;
  int wid = t >> 6, mw = wid >> 1, nw = wid & 1;
  int bid = blockIdx.x;                  // 3072 = 8 xcd * (128 pgrp * 3 m)
  int xcd = bid & 7, rr = bid >> 3;
  int mt = rr % 3, pgrp = rr / 3;
  int M0 = mt * 128;
  size_t N0 = (size_t)(pgrp * 8 + xcd) * 128;
  f32x4 acc[4][4];
  #pragma unroll
  for (int i = 0; i < 4; ++i)
    #pragma unroll
    for (int j = 0; j < 4; ++j) acc[i][j] = (f32x4){0.f, 0.f, 0.f, 0.f};
  for (int kc = 0; kc < 8; ++kc){
    __syncthreads();
    for (int i = t; i < 1536; i += 256){
      int m = i / 12, c = i % 12;
      u32x4 v = *(const u32x4*)&Aun[(size_t)(M0 + m) * 768 + kc * 96 + c * 8];
      *(u32x4*)(lds + m * 208 + c * 16) = v;
    }
    for (int i = t; i < 1536; i += 256){
      int px = i / 12, c = i % 12;
      u32x4 v = *(const u32x4*)&sum[(N0 + px) * 768 + kc * 96 + c * 8];
      *(u32x4*)(lds + 26624 + px * 208 + c * 16) = v;
    }
    __syncthreads();
    #pragma unroll
    for (int ks = 0; ks < 3; ++ks){
      short8 af[4], bfr[4];
      #pragma unroll
      for (int mf = 0; mf < 4; ++mf)
        af[mf] = *(const short8*)(lds + (mw * 64 + mf * 16 + (lane & 15)) * 208 + ks * 64 + (lane >> 4) * 16);
      #pragma unroll
      for (int nf = 0; nf < 4; ++nf)
        bfr[nf] = *(const short8*)(lds + 26624 + (nw * 64 + nf * 16 + (lane & 15)) * 208 + ks * 64 + (lane >> 4) * 16);
      #pragma unroll
      for (int mf = 0; mf < 4; ++mf)
        #pragma unroll
        for (int nf = 0; nf < 4; ++nf)
          acc[mf][nf] = __builtin_amdgcn_mfma_f32_16x16x32_bf16(af[mf], bfr[nf], acc[mf][nf], 0, 0, 0);
    }
  }
  #pragma unroll
  for (int mf = 0; mf < 4; ++mf)
    #pragma unroll
    for (int nf = 0; nf < 4; ++nf){
      int m = M0 + mw * 64 + mf * 16 + (lane >> 4) * 4;   // multiple of 4
      int co = m >> 2;
      size_t px = N0 + nw * 64 + nf * 16 + (lane & 15);
      int b = (int)(px >> 14); int pxl = (int)(px & 16383);
      int hp = pxl >> 7, wp = pxl & 127;
      float bias = bun[co];
      f32x2 v01 = { acc[mf][nf][0] + bias, acc[mf][nf][1] + bias };
      f32x2 v23 = { acc[mf][nf][2] + bias, acc[mf][nf][3] + bias };
      size_t ob = (((size_t)b * 96 + co) * 256 + 2 * hp) * 256 + 2 * wp;
      *(f32x2*)&out[ob]       = v01;   // row 2hp,   cols 2wp..2wp+1 (q=0,1)
      *(f32x2*)&out[ob + 256] = v23;   // row 2hp+1
    }
}

// ---------------------------------------------------------------------------
extern "C" void kernel_launch(void* const* d_in, const int* in_sizes, int n_in,
                              void* d_out, int out_size, void* d_ws, size_t ws_size,
                              hipStream_t stream){
  (void)in_sizes; (void)n_in; (void)out_size;
  const float* x    = (const float*)d_in[0];
  const float* rpw  = (const float*)d_in[1];
  const float* rpb  = (const float*)d_in[2];
  const float* cpw  = (const float*)d_in[3];
  const float* cpb  = (const float*)d_in[4];
  const float* rpew = (const float*)d_in[5];
  const float* rpeb = (const float*)d_in[6];
  const float* cpew = (const float*)d_in[7];
  const float* cpeb = (const float*)d_in[8];
  const float* runw = (const float*)d_in[9];
  const float* runb = (const float*)d_in[10];
  const float* cunw = (const float*)d_in[11];
  const float* cunb = (const float*)d_in[12];
  const float* rgw  = (const float*)d_in[13];
  const float* cgw  = (const float*)d_in[14];

  char* ws = (char*)d_ws;
  const size_t SZ_XT   = (size_t)8 * 260 * 260 * 128 * 2;   // 138,444,800
  const size_t OFF_A3  = SZ_XT;
  const size_t SZ_A3   = (size_t)768 * 2400 * 2;
  const size_t OFF_AUN = OFF_A3 + SZ_A3;
  const size_t SZ_AUN  = (size_t)384 * 768 * 2;
  const size_t OFF_AGR = OFF_AUN + SZ_AUN;
  const size_t SZ_AGR  = (size_t)2 * 192 * 96 * 2;
  const size_t OFF_BUN = OFF_AGR + SZ_AGR;
  const size_t OFF_HG  = ((OFF_BUN + 384) + 255) & ~(size_t)255;
  const size_t SZ_PL   = (size_t)8 * 768 * 128 * 128 * 2;   // 201,326,592
  const size_t OFF_CL  = OFF_HG + SZ_PL;
  const size_t OFF_SUM = OFF_CL + SZ_PL;
  const size_t NEED    = OFF_SUM + SZ_PL;                   // ~747 MB
  if (ws_size < NEED){
    fprintf(stderr, "kernel_launch: ws_size %zu < needed %zu\n", ws_size, NEED);
    return;
  }
  unsigned short* xt  = (unsigned short*)(ws);
  unsigned short* A3  = (unsigned short*)(ws + OFF_A3);
  unsigned short* Aun = (unsigned short*)(ws + OFF_AUN);
  unsigned short* Agr = (unsigned short*)(ws + OFF_AGR);
  float*          bun = (float*)(ws + OFF_BUN);
  unsigned short* cl  = (unsigned short*)(ws + OFF_CL);
  unsigned short* sum = (unsigned short*)(ws + OFF_SUM);
  float* out = (float*)d_out;

  hipMemsetAsync(xt, 0, SZ_XT, stream);
  k_xt  <<<dim3(8192),    dim3(256), 0, stream>>>(x, xt);
  k_pack<<<dim3(8497),    dim3(256), 0, stream>>>(rpw, cpw, runw, cunw, runb, cunb, rgw, cgw, A3, Aun, Agr, bun);
  k_conv<<<dim3(6144),    dim3(256), 0, stream>>>(xt, A3, rpb, cpb, cl);
  k_pe  <<<dim3(8192),    dim3(256), 0, stream>>>(cl, rpew, cpew, rpeb, cpeb, sum);
  k_gruf<<<dim3(512),     dim3(256), 0, stream>>>(cl, Agr, sum);
  k_unpatch<<<dim3(3072), dim3(256), 0, stream>>>(sum, Aun, bun, out);
}

// Round 15
// 1688.156 us; speedup vs baseline: 1.2359x; 1.2359x over previous
//
#include <hip/hip_runtime.h>
#include <stdint.h>
#include <stdio.h>

typedef __attribute__((ext_vector_type(8))) short short8;
typedef __attribute__((ext_vector_type(4))) float f32x4;
typedef __attribute__((ext_vector_type(2))) float f32x2;
typedef __attribute__((ext_vector_type(4))) unsigned int u32x4;
typedef __attribute__((ext_vector_type(4))) unsigned short u16x4;

#define DEV static __device__ __forceinline__

DEV unsigned short f2bf(float f){
  unsigned u = __float_as_uint(f);
  u += 0x7FFFu + ((u >> 16) & 1u);          // RNE
  return (unsigned short)(u >> 16);
}
DEV float bf2f(unsigned short h){ return __uint_as_float(((unsigned)h) << 16); }

// ---------------------------------------------------------------------------
// x (8,96,256,256) f32  ->  xt (8,260,260,128) bf16 channels-last with halo=2
// ---------------------------------------------------------------------------
__global__ __launch_bounds__(256) void k_xt(const float* __restrict__ x,
                                            unsigned short* __restrict__ xt){
  int bid = blockIdx.x;                 // 8*256*4
  int wq = bid & 3, h = (bid >> 2) & 255, b = bid >> 10;
  int w0 = wq * 64;
  __shared__ unsigned short s[64 * 104];
  int t = threadIdx.x;
  int wl = t & 63, cq = t >> 6;         // cq 0..3
  const float* xp = x + ((size_t)b * 96 * 256 + h) * 256 + w0 + wl;
  #pragma unroll
  for (int i = 0; i < 24; ++i){
    int c = cq + i * 4;                 // 0..95
    s[wl * 104 + c] = f2bf(xp[(size_t)c * 65536]);
  }
  __syncthreads();
  unsigned short* dst = xt + (((size_t)b * 260 + h + 2) * 260 + (w0 + 2)) * 128;
  #pragma unroll
  for (int p = 0; p < 3; ++p){
    int i = t + p * 256;                // 0..767 = 64 w * 12 chunks
    int w = i / 12, ch = i % 12;
    u32x4 v = *(const u32x4*)&s[w * 104 + ch * 8];
    *(u32x4*)&dst[(size_t)w * 128 + ch * 8] = v;
  }
}

// ---------------------------------------------------------------------------
// weight repack (bf16):
//  A2  [768][ (kh*5+kw)*96 + ic ]   patch-conv weights (r then c)
//  Aun [m=co*4+p*2+q][ci 0..767]    unpatch weights
//  Agr [side][m 0..191][k 0..95]    gru weights transposed
//  bun [96] f32 = r_un_b + c_un_b
// ---------------------------------------------------------------------------
__global__ __launch_bounds__(256) void k_pack(const float* __restrict__ rpw, const float* __restrict__ cpw,
    const float* __restrict__ runw, const float* __restrict__ cunw,
    const float* __restrict__ runb, const float* __restrict__ cunb,
    const float* __restrict__ rgw,  const float* __restrict__ cgw,
    unsigned short* __restrict__ A2, unsigned short* __restrict__ Aun,
    unsigned short* __restrict__ Agr, float* __restrict__ bun){
  int tid = blockIdx.x * 256 + threadIdx.x;
  const int NA2 = 768 * 2400, NUN = 384 * 768, NGR = 2 * 192 * 96;
  if (tid < NA2){
    int oc = tid / 2400, r = tid % 2400;
    int kh = r / 480, kw = (r / 96) % 5, ic = r % 96;
    const float* W = oc < 384 ? rpw : cpw;
    int o = oc < 384 ? oc : oc - 384;
    A2[tid] = f2bf(W[(((size_t)o * 96 + ic) * 5 + kh) * 5 + kw]);
  } else if (tid < NA2 + NUN){
    int i = tid - NA2;
    int m = i / 768, ci = i % 768;
    int co = m >> 2, p = (m >> 1) & 1, q = m & 1;
    const float* W = ci < 384 ? runw : cunw;
    int c = ci < 384 ? ci : ci - 384;
    Aun[i] = f2bf(W[(((size_t)c * 96 + co) * 2 + p) * 2 + q]);
  } else if (tid < NA2 + NUN + NGR){
    int i = tid - NA2 - NUN;
    int side = i / 18432, r = i % 18432;
    int m = r / 96, k = r % 96;
    const float* W = side ? cgw : rgw;       // (96,192) row-major
    Agr[i] = f2bf(W[k * 192 + m]);
  } else if (tid < NA2 + NUN + NGR + 96){
    int co = tid - NA2 - NUN - NGR;
    bun[co] = runb[co] + cunb[co];
  }
}

// ---------------------------------------------------------------------------
// patch conv as implicit GEMM, v7 (validated rounds 11-12; BEST: 742 us).
// 1D grid 3072: bid = xcd + 8*(6*pgrp + m) -> the 6 M-tiles of one pixel
// tile are consecutive on the SAME XCD (B-tile L2 reuse).
// ONE 512-thread block = 8 waves (2 mw x 4 nw), block tile 128oc x 256px,
// wave 64oc x 64px.  B per kh: [4 rows][131 cols][16ch x 16B], XOR swizzle.
// A single-buffered LDS [128][208B], async reg-prefetch.  2 barriers/slab.
// Epilogue S-write swizzled (oc ^ ((px&7)<<3)).
// ---------------------------------------------------------------------------
__global__ __launch_bounds__(512) void k_conv(const unsigned short* __restrict__ xt,
    const unsigned short* __restrict__ A2,
    const float* __restrict__ rpb, const float* __restrict__ cpb,
    unsigned short* __restrict__ cl){
  __shared__ char lds[160768];
  const int BOFF = 26624;               // B region offset
  const int BPITCH = 33536;             // 131 cols * 256 B
  const int BITEMS = 8384;              // 4 rows * 131 cols * 16 ch
  int t = threadIdx.x, lane = t & 63;
  int wid = t >> 6, mw = wid >> 2, nw = wid & 3;
  int wl = lane & 15, cg = lane >> 4;
  int bid = blockIdx.x;                 // 3072 = 8 xcd * (64 pgrp * 6 m)
  int xcd = bid & 7, rr = bid >> 3;
  int mt = rr % 6, pgrp = rr / 6;
  int p = pgrp * 8 + xcd;               // pixel tile 0..511
  int wq = p & 1, hq = (p >> 1) & 31, b = p >> 6;
  int ho0 = hq * 4, wo0 = wq * 64;
  int M0 = mt * 128;

  // A staging role: oc = t>>2 (0..127), quarter = t&3 (24 elems each)
  int a_oc = t >> 2, a_q = t & 3;
  const unsigned short* Aoc = A2 + (size_t)(M0 + a_oc) * 2400 + a_q * 24;
  char* Adst = lds + a_oc * 208 + a_q * 48;

  f32x4 acc[4][4];
  #pragma unroll
  for (int i = 0; i < 4; ++i)
    #pragma unroll
    for (int j = 0; j < 4; ++j) acc[i][j] = (f32x4){0.f, 0.f, 0.f, 0.f};

  u32x4 aR[3], bR[17];
  // ---- prologue: A(0,0) + B(kh=0) ----
  #pragma unroll
  for (int c = 0; c < 3; ++c) aR[c] = *(const u32x4*)(Aoc + c * 8);
  #pragma unroll
  for (int it = 0; it < 17; ++it){
    int i = t + it * 512;
    if (i < BITEMS){
      int row = i / 2096, j = i % 2096, col = j >> 4, ch = j & 15;
      bR[it] = *(const u32x4*)&xt[(((size_t)b * 260 + 2 * ho0 + 2 * row) * 260 + 2 * wo0 + col) * 128 + ch * 8];
    }
  }
  #pragma unroll
  for (int c = 0; c < 3; ++c) *(u32x4*)(Adst + c * 16) = aR[c];
  #pragma unroll
  for (int it = 0; it < 17; ++it){
    int i = t + it * 512;
    if (i < BITEMS){
      int row = i / 2096, j = i % 2096, col = j >> 4, ch = j & 15;
      *(u32x4*)(lds + BOFF + row * BPITCH + col * 256 + (ch ^ ((col >> 1) & 7)) * 16) = bR[it];
    }
  }
  __syncthreads();

  for (int kh = 0; kh < 5; ++kh){
    #pragma unroll
    for (int kw = 0; kw < 5; ++kw){
      bool last = (kh == 4 && kw == 4);
      bool khb  = (kw == 4 && kh < 4);
      if (!last){
        int nkh = kh + (kw == 4 ? 1 : 0), nkw = (kw == 4 ? 0 : kw + 1);
        const unsigned short* As = Aoc + (nkh * 5 + nkw) * 96;
        #pragma unroll
        for (int c = 0; c < 3; ++c) aR[c] = *(const u32x4*)(As + c * 8);
      }
      if (khb){
        #pragma unroll
        for (int it = 0; it < 17; ++it){
          int i = t + it * 512;
          if (i < BITEMS){
            int row = i / 2096, j = i % 2096, col = j >> 4, ch = j & 15;
            bR[it] = *(const u32x4*)&xt[(((size_t)b * 260 + 2 * ho0 + 2 * row + kh + 1) * 260 + 2 * wo0 + col) * 128 + ch * 8];
          }
        }
      }
      {
        int col = 32 * nw + 2 * wl + kw;
        int sx = (col >> 1) & 7;
        #pragma unroll
        for (int ics = 0; ics < 3; ++ics){
          short8 af[4], bfr[4];
          #pragma unroll
          for (int mf = 0; mf < 4; ++mf)
            af[mf] = *(const short8*)(lds + (mw * 64 + mf * 16 + wl) * 208 + ics * 64 + cg * 16);
          int chl = (ics * 4 + cg) ^ sx;
          #pragma unroll
          for (int nf = 0; nf < 4; ++nf)
            bfr[nf] = *(const short8*)(lds + BOFF + nf * BPITCH + col * 256 + chl * 16);
          #pragma unroll
          for (int mf = 0; mf < 4; ++mf)
            #pragma unroll
            for (int nf = 0; nf < 4; ++nf)
              acc[mf][nf] = __builtin_amdgcn_mfma_f32_16x16x32_bf16(af[mf], bfr[nf], acc[mf][nf], 0, 0, 0);
        }
      }
      __syncthreads();
      if (!last){
        #pragma unroll
        for (int c = 0; c < 3; ++c) *(u32x4*)(Adst + c * 16) = aR[c];
        if (khb){
          #pragma unroll
          for (int it = 0; it < 17; ++it){
            int i = t + it * 512;
            if (i < BITEMS){
              int row = i / 2096, j = i % 2096, col = j >> 4, ch = j & 15;
              *(u32x4*)(lds + BOFF + row * BPITCH + col * 256 + (ch ^ ((col >> 1) & 7)) * 16) = bR[it];
            }
          }
        }
      }
      __syncthreads();
    }
  }
  // epilogue: bias, stash to LDS [256 px][128 oc] (swizzled), coop cl write
  unsigned short* S = (unsigned short*)lds;
  #pragma unroll
  for (int mf = 0; mf < 4; ++mf)
    #pragma unroll
    for (int nf = 0; nf < 4; ++nf){
      int wol = nw * 16 + wl;
      int pxl = nf * 64 + wol;
      int sw8 = (pxl & 7) << 3;
      #pragma unroll
      for (int j = 0; j < 4; ++j){
        int ocl = mw * 64 + mf * 16 + cg * 4 + j;
        int oc = M0 + ocl;
        float v = acc[mf][nf][j] + (oc < 384 ? rpb[oc] : cpb[oc - 384]);
        S[pxl * 128 + (ocl ^ sw8)] = f2bf(v);
      }
    }
  __syncthreads();
  #pragma unroll
  for (int it = 0; it < 8; ++it){
    int i = t + it * 512;               // 0..4095 = 256 px * 16 chunks
    int pxl = i >> 4, ch = i & 15;
    int chs = ch ^ (pxl & 7);
    int ho = ho0 + (pxl >> 6), wo = wo0 + (pxl & 63);
    u32x4 v = *(const u32x4*)&S[pxl * 128 + chs * 8];
    *(u32x4*)&cl[(((size_t)b * 128 + ho) * 128 + wo) * 768 + M0 + ch * 8] = v;
  }
}

// ---------------------------------------------------------------------------
// positional grouped conv 3x3, v2 (validated rounds 12-14).
// ---------------------------------------------------------------------------
__global__ __launch_bounds__(256) void k_pe(const unsigned short* __restrict__ cl,
    const float* __restrict__ rpew, const float* __restrict__ cpew,
    const float* __restrict__ rpeb, const float* __restrict__ cpeb,
    unsigned short* __restrict__ sum){
  __shared__ unsigned short si[340 * 52];  // [pix = r2*34+cc][ch pitch 52]
  __shared__ float sw[48 * 36];
  __shared__ float sb[48];
  int bid = blockIdx.x;                    // 8*16*16*4
  int wq = bid & 3, hq = (bid >> 2) & 15, slab = (bid >> 6) & 15, b = bid >> 10;
  int ch0 = slab * 48, hp0 = hq * 8, wp0 = wq * 32;
  int t = threadIdx.x;
  for (int i = t; i < 48 * 36; i += 256){
    int ocl = i / 36, r = i % 36;
    int oc = ch0 + ocl;
    const float* W = oc < 384 ? rpew : cpew;
    int o = oc < 384 ? oc : oc - 384;
    sw[i] = W[(size_t)o * 36 + r];
  }
  if (t < 48){
    int oc = ch0 + t;
    sb[t] = oc < 384 ? rpeb[oc] : cpeb[oc - 384];
  }
  for (int i = t; i < 340 * 24; i += 256){   // u32 = 2 ch at a time
    int pix = i / 24, c2 = i % 24;
    int r2 = pix / 34, cc = pix % 34;
    int hp = hp0 - 1 + r2, wp = wp0 - 1 + cc;
    unsigned v = 0;
    if (hp >= 0 && hp < 128 && wp >= 0 && wp < 128)
      v = *(const unsigned*)&cl[((size_t)b * 16384 + hp * 128 + wp) * 768 + ch0 + c2 * 2];
    *(unsigned*)&si[pix * 52 + c2 * 2] = v;
  }
  __syncthreads();
  int hpl = t >> 5, wpl = t & 31;
  unsigned int outp[24];
  #pragma unroll
  for (int g = 0; g < 12; ++g){
    float o0 = sb[g * 4], o1 = sb[g * 4 + 1], o2 = sb[g * 4 + 2], o3 = sb[g * 4 + 3];
    #pragma unroll
    for (int dh = 0; dh < 3; ++dh)
      #pragma unroll
      for (int dw = 0; dw < 3; ++dw){
        int pix = (hpl + dh) * 34 + (wpl + dw);
        u16x4 v = *(const u16x4*)&si[pix * 52 + g * 4];
        float x0 = bf2f(v[0]), x1 = bf2f(v[1]), x2 = bf2f(v[2]), x3 = bf2f(v[3]);
        int r = dh * 3 + dw;
        o0 = fmaf(sw[(g*4+0)*36 + 0*9 + r], x0, o0); o0 = fmaf(sw[(g*4+0)*36 + 1*9 + r], x1, o0);
        o0 = fmaf(sw[(g*4+0)*36 + 2*9 + r], x2, o0); o0 = fmaf(sw[(g*4+0)*36 + 3*9 + r], x3, o0);
        o1 = fmaf(sw[(g*4+1)*36 + 0*9 + r], x0, o1); o1 = fmaf(sw[(g*4+1)*36 + 1*9 + r], x1, o1);
        o1 = fmaf(sw[(g*4+1)*36 + 2*9 + r], x2, o1); o1 = fmaf(sw[(g*4+1)*36 + 3*9 + r], x3, o1);
        o2 = fmaf(sw[(g*4+2)*36 + 0*9 + r], x0, o2); o2 = fmaf(sw[(g*4+2)*36 + 1*9 + r], x1, o2);
        o2 = fmaf(sw[(g*4+2)*36 + 2*9 + r], x2, o2); o2 = fmaf(sw[(g*4+2)*36 + 3*9 + r], x3, o2);
        o3 = fmaf(sw[(g*4+3)*36 + 0*9 + r], x0, o3); o3 = fmaf(sw[(g*4+3)*36 + 1*9 + r], x1, o3);
        o3 = fmaf(sw[(g*4+3)*36 + 2*9 + r], x2, o3); o3 = fmaf(sw[(g*4+3)*36 + 3*9 + r], x3, o3);
      }
    outp[g * 2]     = (unsigned)f2bf(o0) | ((unsigned)f2bf(o1) << 16);
    outp[g * 2 + 1] = (unsigned)f2bf(o2) | ((unsigned)f2bf(o3) << 16);
  }
  size_t obase = (((size_t)b * 128 + hp0 + hpl) * 128 + wp0 + wpl) * 768 + ch0;
  #pragma unroll
  for (int c6 = 0; c6 < 6; ++c6){
    u32x4 v = { outp[c6 * 4], outp[c6 * 4 + 1], outp[c6 * 4 + 2], outp[c6 * 4 + 3] };
    *(u32x4*)&sum[obase + c6 * 8] = v;
  }
}

// ---------------------------------------------------------------------------
// FUSED hg-GEMM + minGRU scan (validated rounds 12-14).
// ---------------------------------------------------------------------------
__global__ __launch_bounds__(256) void k_gruf(const unsigned short* __restrict__ cl,
    const unsigned short* __restrict__ Agr, unsigned short* __restrict__ sum){
  __shared__ char lds[78848];
  const int AOFF = 0, BOFF2 = 39936, HOFF = 53248;
  int t = threadIdx.x, lane = t & 63, wid = t >> 6;
  int wl = lane & 15, cg = lane >> 4;
  int bid = blockIdx.x;
  int cb = bid & 7, head = (bid >> 3) & 3, b = (bid >> 5) & 7, side = bid >> 8;
  size_t clbase = ((size_t)b * 16384) * 768 + side * 384 + head * 96;
  for (int i = t; i < 2304; i += 256){
    int m = i / 12, c = i % 12;
    u32x4 v = *(const u32x4*)&Agr[((size_t)side * 192 + m) * 96 + c * 8];
    *(u32x4*)(lds + AOFF + m * 208 + c * 16) = v;
  }
  for (int i = t; i < 768; i += 256){
    int px = i / 12, c = i % 12;
    int s = px >> 4, xl = px & 15;
    int xg = cb * 16 + xl;
    int pxg = side ? (xg * 128 + s) : (s * 128 + xg);
    u32x4 v = *(const u32x4*)&cl[clbase + (size_t)pxg * 768 + c * 8];
    *(u32x4*)(lds + BOFF2 + px * 208 + c * 16) = v;
  }
  int s_chain = t & 15, s_dg = t >> 4;    // scan role: active if s_dg < 12
  float h[8];
  #pragma unroll
  for (int k = 0; k < 8; ++k) h[k] = 0.f;
  __syncthreads();

  for (int ch = 0; ch < 32; ++ch){
    int s0 = ch * 4;
    f32x4 acc[12];
    #pragma unroll
    for (int i = 0; i < 12; ++i) acc[i] = (f32x4){0.f, 0.f, 0.f, 0.f};
    #pragma unroll
    for (int ks = 0; ks < 3; ++ks){
      short8 bf = *(const short8*)(lds + BOFF2 + (wid * 16 + wl) * 208 + ks * 64 + cg * 16);
      #pragma unroll
      for (int mf = 0; mf < 12; ++mf){
        short8 af = *(const short8*)(lds + AOFF + (mf * 16 + wl) * 208 + ks * 64 + cg * 16);
        acc[mf] = __builtin_amdgcn_mfma_f32_16x16x32_bf16(af, bf, acc[mf], 0, 0, 0);
      }
    }
    {
      int px = wid * 16 + wl;
      #pragma unroll
      for (int mf = 0; mf < 12; ++mf){
        unsigned p0 = (unsigned)f2bf(acc[mf][0]) | ((unsigned)f2bf(acc[mf][1]) << 16);
        unsigned p1 = (unsigned)f2bf(acc[mf][2]) | ((unsigned)f2bf(acc[mf][3]) << 16);
        unsigned long long pp = (unsigned long long)p0 | ((unsigned long long)p1 << 32);
        *(unsigned long long*)(lds + HOFF + px * 400 + (mf * 16 + cg * 4) * 2) = pp;
      }
    }
    __syncthreads();
    if (s_dg < 12){
      #pragma unroll
      for (int s = 0; s < 4; ++s){
        int px = s * 16 + s_chain;
        short8 hid8 = *(const short8*)(lds + HOFF + px * 400 + s_dg * 16);
        short8 gat8 = *(const short8*)(lds + HOFF + px * 400 + 192 + s_dg * 16);
        int xg = cb * 16 + s_chain;
        int pxg = side ? (xg * 128 + (s0 + s)) : ((s0 + s) * 128 + xg);
        unsigned short* sp = (unsigned short*)&sum[clbase + (size_t)pxg * 768 + s_dg * 8];
        u32x4 sv = *(u32x4*)sp;
        unsigned short* svp = (unsigned short*)&sv;
        #pragma unroll
        for (int k = 0; k < 8; ++k){
          float hid = bf2f((unsigned short)hid8[k]);
          float gat = bf2f((unsigned short)gat8[k]);
          float z  = 1.f / (1.f + __expf(-gat));
          float th = hid >= 0.f ? hid + 0.5f : 1.f / (1.f + __expf(-hid));
          h[k] += z * (th - h[k]);
          svp[k] = f2bf(bf2f(svp[k]) + h[k]);
        }
        *(u32x4*)sp = sv;
      }
    }
    if (ch < 31){
      int sn = (ch + 1) * 4;
      for (int i = t; i < 768; i += 256){
        int px = i / 12, c = i % 12;
        int s = px >> 4, xl = px & 15;
        int xg = cb * 16 + xl;
        int pxg = side ? (xg * 128 + (sn + s)) : ((sn + s) * 128 + xg);
        u32x4 v = *(const u32x4*)&cl[clbase + (size_t)pxg * 768 + c * 8];
        *(u32x4*)(lds + BOFF2 + px * 208 + c * 16) = v;
      }
    }
    __syncthreads();
  }
}

// ---------------------------------------------------------------------------
// unpatch, v3 (validated rounds 13-14): XCD-grouped grid + paired f32x2 stores.
// ---------------------------------------------------------------------------
__global__ __launch_bounds__(256) void k_unpatch(const unsigned short* __restrict__ sum,
    const unsigned short* __restrict__ Aun, const float* __restrict__ bun,
    float* __restrict__ out){
  __shared__ char lds[53248];            // A [128][208B] | B [128][208B]
  int t = threadIdx.x, lane = t & 63;
  int wid = t >> 6, mw = wid >> 1, nw = wid & 1;
  int bid = blockIdx.x;                  // 3072 = 8 xcd * (128 pgrp * 3 m)
  int xcd = bid & 7, rr = bid >> 3;
  int mt = rr % 3, pgrp = rr / 3;
  int M0 = mt * 128;
  size_t N0 = (size_t)(pgrp * 8 + xcd) * 128;
  f32x4 acc[4][4];
  #pragma unroll
  for (int i = 0; i < 4; ++i)
    #pragma unroll
    for (int j = 0; j < 4; ++j) acc[i][j] = (f32x4){0.f, 0.f, 0.f, 0.f};
  for (int kc = 0; kc < 8; ++kc){
    __syncthreads();
    for (int i = t; i < 1536; i += 256){
      int m = i / 12, c = i % 12;
      u32x4 v = *(const u32x4*)&Aun[(size_t)(M0 + m) * 768 + kc * 96 + c * 8];
      *(u32x4*)(lds + m * 208 + c * 16) = v;
    }
    for (int i = t; i < 1536; i += 256){
      int px = i / 12, c = i % 12;
      u32x4 v = *(const u32x4*)&sum[(N0 + px) * 768 + kc * 96 + c * 8];
      *(u32x4*)(lds + 26624 + px * 208 + c * 16) = v;
    }
    __syncthreads();
    #pragma unroll
    for (int ks = 0; ks < 3; ++ks){
      short8 af[4], bfr[4];
      #pragma unroll
      for (int mf = 0; mf < 4; ++mf)
        af[mf] = *(const short8*)(lds + (mw * 64 + mf * 16 + (lane & 15)) * 208 + ks * 64 + (lane >> 4) * 16);
      #pragma unroll
      for (int nf = 0; nf < 4; ++nf)
        bfr[nf] = *(const short8*)(lds + 26624 + (nw * 64 + nf * 16 + (lane & 15)) * 208 + ks * 64 + (lane >> 4) * 16);
      #pragma unroll
      for (int mf = 0; mf < 4; ++mf)
        #pragma unroll
        for (int nf = 0; nf < 4; ++nf)
          acc[mf][nf] = __builtin_amdgcn_mfma_f32_16x16x32_bf16(af[mf], bfr[nf], acc[mf][nf], 0, 0, 0);
    }
  }
  #pragma unroll
  for (int mf = 0; mf < 4; ++mf)
    #pragma unroll
    for (int nf = 0; nf < 4; ++nf){
      int m = M0 + mw * 64 + mf * 16 + (lane >> 4) * 4;   // multiple of 4
      int co = m >> 2;
      size_t px = N0 + nw * 64 + nf * 16 + (lane & 15);
      int b = (int)(px >> 14); int pxl = (int)(px & 16383);
      int hp = pxl >> 7, wp = pxl & 127;
      float bias = bun[co];
      f32x2 v01 = { acc[mf][nf][0] + bias, acc[mf][nf][1] + bias };
      f32x2 v23 = { acc[mf][nf][2] + bias, acc[mf][nf][3] + bias };
      size_t ob = (((size_t)b * 96 + co) * 256 + 2 * hp) * 256 + 2 * wp;
      *(f32x2*)&out[ob]       = v01;   // row 2hp,   cols 2wp..2wp+1 (q=0,1)
      *(f32x2*)&out[ob + 256] = v23;   // row 2hp+1
    }
}

// ---------------------------------------------------------------------------
extern "C" void kernel_launch(void* const* d_in, const int* in_sizes, int n_in,
                              void* d_out, int out_size, void* d_ws, size_t ws_size,
                              hipStream_t stream){
  (void)in_sizes; (void)n_in; (void)out_size;
  const float* x    = (const float*)d_in[0];
  const float* rpw  = (const float*)d_in[1];
  const float* rpb  = (const float*)d_in[2];
  const float* cpw  = (const float*)d_in[3];
  const float* cpb  = (const float*)d_in[4];
  const float* rpew = (const float*)d_in[5];
  const float* rpeb = (const float*)d_in[6];
  const float* cpew = (const float*)d_in[7];
  const float* cpeb = (const float*)d_in[8];
  const float* runw = (const float*)d_in[9];
  const float* runb = (const float*)d_in[10];
  const float* cunw = (const float*)d_in[11];
  const float* cunb = (const float*)d_in[12];
  const float* rgw  = (const float*)d_in[13];
  const float* cgw  = (const float*)d_in[14];

  char* ws = (char*)d_ws;
  const size_t SZ_XT   = (size_t)8 * 260 * 260 * 128 * 2;   // 138,444,800
  const size_t OFF_A2  = SZ_XT;
  const size_t SZ_A2   = (size_t)768 * 2400 * 2;
  const size_t OFF_AUN = OFF_A2 + SZ_A2;
  const size_t SZ_AUN  = (size_t)384 * 768 * 2;
  const size_t OFF_AGR = OFF_AUN + SZ_AUN;
  const size_t SZ_AGR  = (size_t)2 * 192 * 96 * 2;
  const size_t OFF_BUN = OFF_AGR + SZ_AGR;
  const size_t OFF_HG  = ((OFF_BUN + 384) + 255) & ~(size_t)255;
  const size_t SZ_PL   = (size_t)8 * 768 * 128 * 128 * 2;   // 201,326,592
  const size_t OFF_CL  = OFF_HG + SZ_PL;
  const size_t OFF_SUM = OFF_CL + SZ_PL;
  const size_t NEED    = OFF_SUM + SZ_PL;                   // ~747 MB
  if (ws_size < NEED){
    fprintf(stderr, "kernel_launch: ws_size %zu < needed %zu\n", ws_size, NEED);
    return;
  }
  unsigned short* xt  = (unsigned short*)(ws);
  unsigned short* A2  = (unsigned short*)(ws + OFF_A2);
  unsigned short* Aun = (unsigned short*)(ws + OFF_AUN);
  unsigned short* Agr = (unsigned short*)(ws + OFF_AGR);
  float*          bun = (float*)(ws + OFF_BUN);
  unsigned short* cl  = (unsigned short*)(ws + OFF_CL);
  unsigned short* sum = (unsigned short*)(ws + OFF_SUM);
  float* out = (float*)d_out;

  hipMemsetAsync(xt, 0, SZ_XT, stream);
  k_xt  <<<dim3(8192),    dim3(256), 0, stream>>>(x, xt);
  k_pack<<<dim3(8497),    dim3(256), 0, stream>>>(rpw, cpw, runw, cunw, runb, cunb, rgw, cgw, A2, Aun, Agr, bun);
  k_conv<<<dim3(3072),    dim3(512), 0, stream>>>(xt, A2, rpb, cpb, cl);
  k_pe  <<<dim3(8192),    dim3(256), 0, stream>>>(cl, rpew, cpew, rpeb, cpeb, sum);
  k_gruf<<<dim3(512),     dim3(256), 0, stream>>>(cl, Agr, sum);
  k_unpatch<<<dim3(3072), dim3(256), 0, stream>>>(sum, Aun, bun, out);
}

// Round 16
// 1485.636 us; speedup vs baseline: 1.4044x; 1.1363x over previous
//
#include <hip/hip_runtime.h>
#include <stdint.h>
#include <stdio.h>

typedef __attribute__((ext_vector_type(8))) short short8;
typedef __attribute__((ext_vector_type(4))) float f32x4;
typedef __attribute__((ext_vector_type(2))) float f32x2;
typedef __attribute__((ext_vector_type(4))) unsigned int u32x4;
typedef __attribute__((ext_vector_type(4))) unsigned short u16x4;

#define DEV static __device__ __forceinline__

DEV unsigned short f2bf(float f){
  unsigned u = __float_as_uint(f);
  u += 0x7FFFu + ((u >> 16) & 1u);          // RNE
  return (unsigned short)(u >> 16);
}
DEV float bf2f(unsigned short h){ return __uint_as_float(((unsigned)h) << 16); }

// ---------------------------------------------------------------------------
// x (8,96,256,256) f32  ->  xt (8,260,260,128) bf16 channels-last with halo=2
// ---------------------------------------------------------------------------
__global__ __launch_bounds__(256) void k_xt(const float* __restrict__ x,
                                            unsigned short* __restrict__ xt){
  int bid = blockIdx.x;                 // 8*256*4
  int wq = bid & 3, h = (bid >> 2) & 255, b = bid >> 10;
  int w0 = wq * 64;
  __shared__ unsigned short s[64 * 104];
  int t = threadIdx.x;
  int wl = t & 63, cq = t >> 6;         // cq 0..3
  const float* xp = x + ((size_t)b * 96 * 256 + h) * 256 + w0 + wl;
  #pragma unroll
  for (int i = 0; i < 24; ++i){
    int c = cq + i * 4;                 // 0..95
    s[wl * 104 + c] = f2bf(xp[(size_t)c * 65536]);
  }
  __syncthreads();
  unsigned short* dst = xt + (((size_t)b * 260 + h + 2) * 260 + (w0 + 2)) * 128;
  #pragma unroll
  for (int p = 0; p < 3; ++p){
    int i = t + p * 256;                // 0..767 = 64 w * 12 chunks
    int w = i / 12, ch = i % 12;
    u32x4 v = *(const u32x4*)&s[w * 104 + ch * 8];
    *(u32x4*)&dst[(size_t)w * 128 + ch * 8] = v;
  }
}

// ---------------------------------------------------------------------------
// weight repack (bf16):
//  A2  [768][ (kh*5+kw)*96 + ic ]   patch-conv weights (r then c)
//  Aun [m=co*4+p*2+q][ci 0..767]    unpatch weights
//  Agr [side][m 0..191][k 0..95]    gru weights transposed
//  bun [96] f32 = r_un_b + c_un_b
// ---------------------------------------------------------------------------
__global__ __launch_bounds__(256) void k_pack(const float* __restrict__ rpw, const float* __restrict__ cpw,
    const float* __restrict__ runw, const float* __restrict__ cunw,
    const float* __restrict__ runb, const float* __restrict__ cunb,
    const float* __restrict__ rgw,  const float* __restrict__ cgw,
    unsigned short* __restrict__ A2, unsigned short* __restrict__ Aun,
    unsigned short* __restrict__ Agr, float* __restrict__ bun){
  int tid = blockIdx.x * 256 + threadIdx.x;
  const int NA2 = 768 * 2400, NUN = 384 * 768, NGR = 2 * 192 * 96;
  if (tid < NA2){
    int oc = tid / 2400, r = tid % 2400;
    int kh = r / 480, kw = (r / 96) % 5, ic = r % 96;
    const float* W = oc < 384 ? rpw : cpw;
    int o = oc < 384 ? oc : oc - 384;
    A2[tid] = f2bf(W[(((size_t)o * 96 + ic) * 5 + kh) * 5 + kw]);
  } else if (tid < NA2 + NUN){
    int i = tid - NA2;
    int m = i / 768, ci = i % 768;
    int co = m >> 2, p = (m >> 1) & 1, q = m & 1;
    const float* W = ci < 384 ? runw : cunw;
    int c = ci < 384 ? ci : ci - 384;
    Aun[i] = f2bf(W[(((size_t)c * 96 + co) * 2 + p) * 2 + q]);
  } else if (tid < NA2 + NUN + NGR){
    int i = tid - NA2 - NUN;
    int side = i / 18432, r = i % 18432;
    int m = r / 96, k = r % 96;
    const float* W = side ? cgw : rgw;       // (96,192) row-major
    Agr[i] = f2bf(W[k * 192 + m]);
  } else if (tid < NA2 + NUN + NGR + 96){
    int co = tid - NA2 - NUN - NGR;
    bun[co] = runb[co] + cunb[co];
  }
}

// ---------------------------------------------------------------------------
// patch conv as implicit GEMM, v10 = v7 geometry + A DOUBLE-BUFFER (barriers
// 50 -> 30) + 208B-pitch B (self-spreading banks, validated round 14).
// 1D grid 3072 XCD-grouped.  512 threads = 8 waves (2mw x 4nw), block tile
// 128oc x 256px (4ho x 64wo), wave 64oc x 64px.
// LDS: A dbuf 2x[128][208B]=53248 | B [4r][131c][208B]=108992 -> 162240.
// Per slab: 1 barrier (A-dbuf removes the hazard barrier); kh-boundary: 2.
// ---------------------------------------------------------------------------
__global__ __launch_bounds__(512) void k_conv(const unsigned short* __restrict__ xt,
    const unsigned short* __restrict__ A2,
    const float* __restrict__ rpb, const float* __restrict__ cpb,
    unsigned short* __restrict__ cl){
  __shared__ char lds[162240];
  const int ASZ = 26624;                // one A buffer [128][208B]
  const int BOFF = 53248;               // B region offset
  const int BPITCH = 27248;             // 131 cols * 208 B
  const int BITEMS = 6288;              // 4 rows * 131 cols * 12 ch
  int t = threadIdx.x, lane = t & 63;
  int wid = t >> 6, mw = wid >> 2, nw = wid & 3;
  int wl = lane & 15, cg = lane >> 4;
  int bid = blockIdx.x;                 // 3072 = 8 xcd * (64 pgrp * 6 m)
  int xcd = bid & 7, rr = bid >> 3;
  int mt = rr % 6, pgrp = rr / 6;
  int p = pgrp * 8 + xcd;               // pixel tile 0..511
  int wq = p & 1, hq = (p >> 1) & 31, b = p >> 6;
  int ho0 = hq * 4, wo0 = wq * 64;
  int M0 = mt * 128;

  // A staging role: oc = t>>2 (0..127), quarter = t&3 (24 elems each)
  int a_oc = t >> 2, a_q = t & 3;
  const unsigned short* Aoc = A2 + (size_t)(M0 + a_oc) * 2400 + a_q * 24;
  char* Adst = lds + a_oc * 208 + a_q * 48;

  f32x4 acc[4][4];
  #pragma unroll
  for (int i = 0; i < 4; ++i)
    #pragma unroll
    for (int j = 0; j < 4; ++j) acc[i][j] = (f32x4){0.f, 0.f, 0.f, 0.f};

  u32x4 aR[3], bR[13];
  // ---- prologue: A(0,0) -> buf0 + B(kh=0) ----
  #pragma unroll
  for (int c = 0; c < 3; ++c) aR[c] = *(const u32x4*)(Aoc + c * 8);
  #pragma unroll
  for (int it = 0; it < 13; ++it){
    int i = t + it * 512;
    if (i < BITEMS){
      int row = i / 1572, j = i % 1572, col = j / 12, ch = j % 12;
      bR[it] = *(const u32x4*)&xt[(((size_t)b * 260 + 2 * ho0 + 2 * row) * 260 + 2 * wo0 + col) * 128 + ch * 8];
    }
  }
  #pragma unroll
  for (int c = 0; c < 3; ++c) *(u32x4*)(Adst + c * 16) = aR[c];
  #pragma unroll
  for (int it = 0; it < 13; ++it){
    int i = t + it * 512;
    if (i < BITEMS){
      int row = i / 1572, j = i % 1572, col = j / 12, ch = j % 12;
      *(u32x4*)(lds + BOFF + row * BPITCH + col * 208 + ch * 16) = bR[it];
    }
  }
  __syncthreads();

  int cur = 0;
  for (int kh = 0; kh < 5; ++kh){
    #pragma unroll
    for (int kw = 0; kw < 5; ++kw){
      bool last = (kh == 4 && kw == 4);
      bool khb  = (kw == 4 && kh < 4);
      // issue next-slab A prefetch (global -> regs)
      if (!last){
        int nkh = kh + (kw == 4 ? 1 : 0), nkw = (kw == 4 ? 0 : kw + 1);
        const unsigned short* As = Aoc + (nkh * 5 + nkw) * 96;
        #pragma unroll
        for (int c = 0; c < 3; ++c) aR[c] = *(const u32x4*)(As + c * 8);
      }
      // issue next-kh B prefetch (global -> regs), hidden under 48 MFMA
      if (khb){
        #pragma unroll
        for (int it = 0; it < 13; ++it){
          int i = t + it * 512;
          if (i < BITEMS){
            int row = i / 1572, j = i % 1572, col = j / 12, ch = j % 12;
            bR[it] = *(const u32x4*)&xt[(((size_t)b * 260 + 2 * ho0 + 2 * row + kh + 1) * 260 + 2 * wo0 + col) * 128 + ch * 8];
          }
        }
      }
      // ---- compute slab (kh,kw) from A[cur]: 48 MFMA per wave ----
      {
        char* Ab = lds + cur * ASZ;
        int col = 32 * nw + 2 * wl + kw;
        #pragma unroll
        for (int ics = 0; ics < 3; ++ics){
          short8 af[4], bfr[4];
          #pragma unroll
          for (int mf = 0; mf < 4; ++mf)
            af[mf] = *(const short8*)(Ab + (mw * 64 + mf * 16 + wl) * 208 + ics * 64 + cg * 16);
          #pragma unroll
          for (int nf = 0; nf < 4; ++nf)
            bfr[nf] = *(const short8*)(lds + BOFF + nf * BPITCH + col * 208 + (ics * 4 + cg) * 16);
          #pragma unroll
          for (int mf = 0; mf < 4; ++mf)
            #pragma unroll
            for (int nf = 0; nf < 4; ++nf)
              acc[mf][nf] = __builtin_amdgcn_mfma_f32_16x16x32_bf16(af[mf], bfr[nf], acc[mf][nf], 0, 0, 0);
        }
      }
      if (khb) __syncthreads();          // all waves done reading B(kh)
      if (!last){
        // A -> inactive buffer (no hazard: cur^1 last read before prev barrier)
        #pragma unroll
        for (int c = 0; c < 3; ++c) *(u32x4*)(Adst + (cur ^ 1) * ASZ + c * 16) = aR[c];
        if (khb){
          #pragma unroll
          for (int it = 0; it < 13; ++it){
            int i = t + it * 512;
            if (i < BITEMS){
              int row = i / 1572, j = i % 1572, col = j / 12, ch = j % 12;
              *(u32x4*)(lds + BOFF + row * BPITCH + col * 208 + ch * 16) = bR[it];
            }
          }
        }
        __syncthreads();                 // staged data visible
        cur ^= 1;
      }
    }
  }
  // epilogue: bias, stash to LDS [256 px][128 oc] (swizzled), coop cl write
  __syncthreads();                       // protect A/B reads before S overwrite
  unsigned short* S = (unsigned short*)lds;
  #pragma unroll
  for (int mf = 0; mf < 4; ++mf)
    #pragma unroll
    for (int nf = 0; nf < 4; ++nf){
      int wol = nw * 16 + wl;
      int pxl = nf * 64 + wol;
      int sw8 = (pxl & 7) << 3;
      #pragma unroll
      for (int j = 0; j < 4; ++j){
        int ocl = mw * 64 + mf * 16 + cg * 4 + j;
        int oc = M0 + ocl;
        float v = acc[mf][nf][j] + (oc < 384 ? rpb[oc] : cpb[oc - 384]);
        S[pxl * 128 + (ocl ^ sw8)] = f2bf(v);
      }
    }
  __syncthreads();
  #pragma unroll
  for (int it = 0; it < 8; ++it){
    int i = t + it * 512;               // 0..4095 = 256 px * 16 chunks
    int pxl = i >> 4, ch = i & 15;
    int chs = ch ^ (pxl & 7);
    int ho = ho0 + (pxl >> 6), wo = wo0 + (pxl & 63);
    u32x4 v = *(const u32x4*)&S[pxl * 128 + chs * 8];
    *(u32x4*)&cl[(((size_t)b * 128 + ho) * 128 + wo) * 768 + M0 + ch * 8] = v;
  }
}

// ---------------------------------------------------------------------------
// positional grouped conv 3x3, v2 (validated rounds 12-15).
// ---------------------------------------------------------------------------
__global__ __launch_bounds__(256) void k_pe(const unsigned short* __restrict__ cl,
    const float* __restrict__ rpew, const float* __restrict__ cpew,
    const float* __restrict__ rpeb, const float* __restrict__ cpeb,
    unsigned short* __restrict__ sum){
  __shared__ unsigned short si[340 * 52];  // [pix = r2*34+cc][ch pitch 52]
  __shared__ float sw[48 * 36];
  __shared__ float sb[48];
  int bid = blockIdx.x;                    // 8*16*16*4
  int wq = bid & 3, hq = (bid >> 2) & 15, slab = (bid >> 6) & 15, b = bid >> 10;
  int ch0 = slab * 48, hp0 = hq * 8, wp0 = wq * 32;
  int t = threadIdx.x;
  for (int i = t; i < 48 * 36; i += 256){
    int ocl = i / 36, r = i % 36;
    int oc = ch0 + ocl;
    const float* W = oc < 384 ? rpew : cpew;
    int o = oc < 384 ? oc : oc - 384;
    sw[i] = W[(size_t)o * 36 + r];
  }
  if (t < 48){
    int oc = ch0 + t;
    sb[t] = oc < 384 ? rpeb[oc] : cpeb[oc - 384];
  }
  for (int i = t; i < 340 * 24; i += 256){   // u32 = 2 ch at a time
    int pix = i / 24, c2 = i % 24;
    int r2 = pix / 34, cc = pix % 34;
    int hp = hp0 - 1 + r2, wp = wp0 - 1 + cc;
    unsigned v = 0;
    if (hp >= 0 && hp < 128 && wp >= 0 && wp < 128)
      v = *(const unsigned*)&cl[((size_t)b * 16384 + hp * 128 + wp) * 768 + ch0 + c2 * 2];
    *(unsigned*)&si[pix * 52 + c2 * 2] = v;
  }
  __syncthreads();
  int hpl = t >> 5, wpl = t & 31;
  unsigned int outp[24];
  #pragma unroll
  for (int g = 0; g < 12; ++g){
    float o0 = sb[g * 4], o1 = sb[g * 4 + 1], o2 = sb[g * 4 + 2], o3 = sb[g * 4 + 3];
    #pragma unroll
    for (int dh = 0; dh < 3; ++dh)
      #pragma unroll
      for (int dw = 0; dw < 3; ++dw){
        int pix = (hpl + dh) * 34 + (wpl + dw);
        u16x4 v = *(const u16x4*)&si[pix * 52 + g * 4];
        float x0 = bf2f(v[0]), x1 = bf2f(v[1]), x2 = bf2f(v[2]), x3 = bf2f(v[3]);
        int r = dh * 3 + dw;
        o0 = fmaf(sw[(g*4+0)*36 + 0*9 + r], x0, o0); o0 = fmaf(sw[(g*4+0)*36 + 1*9 + r], x1, o0);
        o0 = fmaf(sw[(g*4+0)*36 + 2*9 + r], x2, o0); o0 = fmaf(sw[(g*4+0)*36 + 3*9 + r], x3, o0);
        o1 = fmaf(sw[(g*4+1)*36 + 0*9 + r], x0, o1); o1 = fmaf(sw[(g*4+1)*36 + 1*9 + r], x1, o1);
        o1 = fmaf(sw[(g*4+1)*36 + 2*9 + r], x2, o1); o1 = fmaf(sw[(g*4+1)*36 + 3*9 + r], x3, o1);
        o2 = fmaf(sw[(g*4+2)*36 + 0*9 + r], x0, o2); o2 = fmaf(sw[(g*4+2)*36 + 1*9 + r], x1, o2);
        o2 = fmaf(sw[(g*4+2)*36 + 2*9 + r], x2, o2); o2 = fmaf(sw[(g*4+2)*36 + 3*9 + r], x3, o2);
        o3 = fmaf(sw[(g*4+3)*36 + 0*9 + r], x0, o3); o3 = fmaf(sw[(g*4+3)*36 + 1*9 + r], x1, o3);
        o3 = fmaf(sw[(g*4+3)*36 + 2*9 + r], x2, o3); o3 = fmaf(sw[(g*4+3)*36 + 3*9 + r], x3, o3);
      }
    outp[g * 2]     = (unsigned)f2bf(o0) | ((unsigned)f2bf(o1) << 16);
    outp[g * 2 + 1] = (unsigned)f2bf(o2) | ((unsigned)f2bf(o3) << 16);
  }
  size_t obase = (((size_t)b * 128 + hp0 + hpl) * 128 + wp0 + wpl) * 768 + ch0;
  #pragma unroll
  for (int c6 = 0; c6 < 6; ++c6){
    u32x4 v = { outp[c6 * 4], outp[c6 * 4 + 1], outp[c6 * 4 + 2], outp[c6 * 4 + 3] };
    *(u32x4*)&sum[obase + c6 * 8] = v;
  }
}

// ---------------------------------------------------------------------------
// FUSED hg-GEMM + minGRU scan, v2: T14 async split in P2 (issue next-chunk
// B loads BEFORE the scan's exp-chain, ds_write after).  Else identical to
// the round-12..15 validated kernel.
// ---------------------------------------------------------------------------
__global__ __launch_bounds__(256) void k_gruf(const unsigned short* __restrict__ cl,
    const unsigned short* __restrict__ Agr, unsigned short* __restrict__ sum){
  __shared__ char lds[78848];
  const int AOFF = 0, BOFF2 = 39936, HOFF = 53248;
  int t = threadIdx.x, lane = t & 63, wid = t >> 6;
  int wl = lane & 15, cg = lane >> 4;
  int bid = blockIdx.x;
  int cb = bid & 7, head = (bid >> 3) & 3, b = (bid >> 5) & 7, side = bid >> 8;
  size_t clbase = ((size_t)b * 16384) * 768 + side * 384 + head * 96;
  for (int i = t; i < 2304; i += 256){
    int m = i / 12, c = i % 12;
    u32x4 v = *(const u32x4*)&Agr[((size_t)side * 192 + m) * 96 + c * 8];
    *(u32x4*)(lds + AOFF + m * 208 + c * 16) = v;
  }
  for (int i = t; i < 768; i += 256){
    int px = i / 12, c = i % 12;
    int s = px >> 4, xl = px & 15;
    int xg = cb * 16 + xl;
    int pxg = side ? (xg * 128 + s) : (s * 128 + xg);
    u32x4 v = *(const u32x4*)&cl[clbase + (size_t)pxg * 768 + c * 8];
    *(u32x4*)(lds + BOFF2 + px * 208 + c * 16) = v;
  }
  int s_chain = t & 15, s_dg = t >> 4;    // scan role: active if s_dg < 12
  float h[8];
  #pragma unroll
  for (int k = 0; k < 8; ++k) h[k] = 0.f;
  __syncthreads();

  for (int ch = 0; ch < 32; ++ch){
    int s0 = ch * 4;
    // ---- P1: GEMM -> HG ----
    f32x4 acc[12];
    #pragma unroll
    for (int i = 0; i < 12; ++i) acc[i] = (f32x4){0.f, 0.f, 0.f, 0.f};
    #pragma unroll
    for (int ks = 0; ks < 3; ++ks){
      short8 bf = *(const short8*)(lds + BOFF2 + (wid * 16 + wl) * 208 + ks * 64 + cg * 16);
      #pragma unroll
      for (int mf = 0; mf < 12; ++mf){
        short8 af = *(const short8*)(lds + AOFF + (mf * 16 + wl) * 208 + ks * 64 + cg * 16);
        acc[mf] = __builtin_amdgcn_mfma_f32_16x16x32_bf16(af, bf, acc[mf], 0, 0, 0);
      }
    }
    {
      int px = wid * 16 + wl;
      #pragma unroll
      for (int mf = 0; mf < 12; ++mf){
        unsigned p0 = (unsigned)f2bf(acc[mf][0]) | ((unsigned)f2bf(acc[mf][1]) << 16);
        unsigned p1 = (unsigned)f2bf(acc[mf][2]) | ((unsigned)f2bf(acc[mf][3]) << 16);
        unsigned long long pp = (unsigned long long)p0 | ((unsigned long long)p1 << 32);
        *(unsigned long long*)(lds + HOFF + px * 400 + (mf * 16 + cg * 4) * 2) = pp;
      }
    }
    __syncthreads();
    // ---- P2: issue next-chunk B loads (T14), scan, then ds_write ----
    u32x4 nb[3];
    if (ch < 31){
      int sn = (ch + 1) * 4;
      #pragma unroll
      for (int it = 0; it < 3; ++it){
        int i = t + it * 256;             // exactly 768 items
        int px = i / 12, c = i % 12;
        int s = px >> 4, xl = px & 15;
        int xg = cb * 16 + xl;
        int pxg = side ? (xg * 128 + (sn + s)) : ((sn + s) * 128 + xg);
        nb[it] = *(const u32x4*)&cl[clbase + (size_t)pxg * 768 + c * 8];
      }
    }
    if (s_dg < 12){
      #pragma unroll
      for (int s = 0; s < 4; ++s){
        int px = s * 16 + s_chain;
        short8 hid8 = *(const short8*)(lds + HOFF + px * 400 + s_dg * 16);
        short8 gat8 = *(const short8*)(lds + HOFF + px * 400 + 192 + s_dg * 16);
        int xg = cb * 16 + s_chain;
        int pxg = side ? (xg * 128 + (s0 + s)) : ((s0 + s) * 128 + xg);
        unsigned short* sp = (unsigned short*)&sum[clbase + (size_t)pxg * 768 + s_dg * 8];
        u32x4 sv = *(u32x4*)sp;
        unsigned short* svp = (unsigned short*)&sv;
        #pragma unroll
        for (int k = 0; k < 8; ++k){
          float hid = bf2f((unsigned short)hid8[k]);
          float gat = bf2f((unsigned short)gat8[k]);
          float z  = 1.f / (1.f + __expf(-gat));
          float th = hid >= 0.f ? hid + 0.5f : 1.f / (1.f + __expf(-hid));
          h[k] += z * (th - h[k]);
          svp[k] = f2bf(bf2f(svp[k]) + h[k]);
        }
        *(u32x4*)sp = sv;
      }
    }
    if (ch < 31){
      #pragma unroll
      for (int it = 0; it < 3; ++it){
        int i = t + it * 256;
        int px = i / 12, c = i % 12;
        *(u32x4*)(lds + BOFF2 + px * 208 + c * 16) = nb[it];
      }
    }
    __syncthreads();
  }
}

// ---------------------------------------------------------------------------
// unpatch, v3 (validated rounds 13-15): XCD-grouped grid + paired f32x2 stores.
// ---------------------------------------------------------------------------
__global__ __launch_bounds__(256) void k_unpatch(const unsigned short* __restrict__ sum,
    const unsigned short* __restrict__ Aun, const float* __restrict__ bun,
    float* __restrict__ out){
  __shared__ char lds[53248];            // A [128][208B] | B [128][208B]
  int t = threadIdx.x, lane = t & 63;
  int wid = t >> 6, mw = wid >> 1, nw = wid & 1;
  int bid = blockIdx.x;                  // 3072 = 8 xcd * (128 pgrp * 3 m)
  int xcd = bid & 7, rr = bid >> 3;
  int mt = rr % 3, pgrp = rr / 3;
  int M0 = mt * 128;
  size_t N0 = (size_t)(pgrp * 8 + xcd) * 128;
  f32x4 acc[4][4];
  #pragma unroll
  for (int i = 0; i < 4; ++i)
    #pragma unroll
    for (int j = 0; j < 4; ++j) acc[i][j] = (f32x4){0.f, 0.f, 0.f, 0.f};
  for (int kc = 0; kc < 8; ++kc){
    __syncthreads();
    for (int i = t; i < 1536; i += 256){
      int m = i / 12, c = i % 12;
      u32x4 v = *(const u32x4*)&Aun[(size_t)(M0 + m) * 768 + kc * 96 + c * 8];
      *(u32x4*)(lds + m * 208 + c * 16) = v;
    }
    for (int i = t; i < 1536; i += 256){
      int px = i / 12, c = i % 12;
      u32x4 v = *(const u32x4*)&sum[(N0 + px) * 768 + kc * 96 + c * 8];
      *(u32x4*)(lds + 26624 + px * 208 + c * 16) = v;
    }
    __syncthreads();
    #pragma unroll
    for (int ks = 0; ks < 3; ++ks){
      short8 af[4], bfr[4];
      #pragma unroll
      for (int mf = 0; mf < 4; ++mf)
        af[mf] = *(const short8*)(lds + (mw * 64 + mf * 16 + (lane & 15)) * 208 + ks * 64 + (lane >> 4) * 16);
      #pragma unroll
      for (int nf = 0; nf < 4; ++nf)
        bfr[nf] = *(const short8*)(lds + 26624 + (nw * 64 + nf * 16 + (lane & 15)) * 208 + ks * 64 + (lane >> 4) * 16);
      #pragma unroll
      for (int mf = 0; mf < 4; ++mf)
        #pragma unroll
        for (int nf = 0; nf < 4; ++nf)
          acc[mf][nf] = __builtin_amdgcn_mfma_f32_16x16x32_bf16(af[mf], bfr[nf], acc[mf][nf], 0, 0, 0);
    }
  }
  #pragma unroll
  for (int mf = 0; mf < 4; ++mf)
    #pragma unroll
    for (int nf = 0; nf < 4; ++nf){
      int m = M0 + mw * 64 + mf * 16 + (lane >> 4) * 4;   // multiple of 4
      int co = m >> 2;
      size_t px = N0 + nw * 64 + nf * 16 + (lane & 15);
      int b = (int)(px >> 14); int pxl = (int)(px & 16383);
      int hp = pxl >> 7, wp = pxl & 127;
      float bias = bun[co];
      f32x2 v01 = { acc[mf][nf][0] + bias, acc[mf][nf][1] + bias };
      f32x2 v23 = { acc[mf][nf][2] + bias, acc[mf][nf][3] + bias };
      size_t ob = (((size_t)b * 96 + co) * 256 + 2 * hp) * 256 + 2 * wp;
      *(f32x2*)&out[ob]       = v01;   // row 2hp,   cols 2wp..2wp+1 (q=0,1)
      *(f32x2*)&out[ob + 256] = v23;   // row 2hp+1
    }
}

// ---------------------------------------------------------------------------
extern "C" void kernel_launch(void* const* d_in, const int* in_sizes, int n_in,
                              void* d_out, int out_size, void* d_ws, size_t ws_size,
                              hipStream_t stream){
  (void)in_sizes; (void)n_in; (void)out_size;
  const float* x    = (const float*)d_in[0];
  const float* rpw  = (const float*)d_in[1];
  const float* rpb  = (const float*)d_in[2];
  const float* cpw  = (const float*)d_in[3];
  const float* cpb  = (const float*)d_in[4];
  const float* rpew = (const float*)d_in[5];
  const float* rpeb = (const float*)d_in[6];
  const float* cpew = (const float*)d_in[7];
  const float* cpeb = (const float*)d_in[8];
  const float* runw = (const float*)d_in[9];
  const float* runb = (const float*)d_in[10];
  const float* cunw = (const float*)d_in[11];
  const float* cunb = (const float*)d_in[12];
  const float* rgw  = (const float*)d_in[13];
  const float* cgw  = (const float*)d_in[14];

  char* ws = (char*)d_ws;
  const size_t SZ_XT   = (size_t)8 * 260 * 260 * 128 * 2;   // 138,444,800
  const size_t OFF_A2  = SZ_XT;
  const size_t SZ_A2   = (size_t)768 * 2400 * 2;
  const size_t OFF_AUN = OFF_A2 + SZ_A2;
  const size_t SZ_AUN  = (size_t)384 * 768 * 2;
  const size_t OFF_AGR = OFF_AUN + SZ_AUN;
  const size_t SZ_AGR  = (size_t)2 * 192 * 96 * 2;
  const size_t OFF_BUN = OFF_AGR + SZ_AGR;
  const size_t OFF_HG  = ((OFF_BUN + 384) + 255) & ~(size_t)255;
  const size_t SZ_PL   = (size_t)8 * 768 * 128 * 128 * 2;   // 201,326,592
  const size_t OFF_CL  = OFF_HG + SZ_PL;
  const size_t OFF_SUM = OFF_CL + SZ_PL;
  const size_t NEED    = OFF_SUM + SZ_PL;                   // ~747 MB
  if (ws_size < NEED){
    fprintf(stderr, "kernel_launch: ws_size %zu < needed %zu\n", ws_size, NEED);
    return;
  }
  unsigned short* xt  = (unsigned short*)(ws);
  unsigned short* A2  = (unsigned short*)(ws + OFF_A2);
  unsigned short* Aun = (unsigned short*)(ws + OFF_AUN);
  unsigned short* Agr = (unsigned short*)(ws + OFF_AGR);
  float*          bun = (float*)(ws + OFF_BUN);
  unsigned short* cl  = (unsigned short*)(ws + OFF_CL);
  unsigned short* sum = (unsigned short*)(ws + OFF_SUM);
  float* out = (float*)d_out;

  hipMemsetAsync(xt, 0, SZ_XT, stream);
  k_xt  <<<dim3(8192),    dim3(256), 0, stream>>>(x, xt);
  k_pack<<<dim3(8497),    dim3(256), 0, stream>>>(rpw, cpw, runw, cunw, runb, cunb, rgw, cgw, A2, Aun, Agr, bun);
  k_conv<<<dim3(3072),    dim3(512), 0, stream>>>(xt, A2, rpb, cpb, cl);
  k_pe  <<<dim3(8192),    dim3(256), 0, stream>>>(cl, rpew, cpew, rpeb, cpeb, sum);
  k_gruf<<<dim3(512),     dim3(256), 0, stream>>>(cl, Agr, sum);
  k_unpatch<<<dim3(3072), dim3(256), 0, stream>>>(sum, Aun, bun, out);
}

// Round 17
// 1428.025 us; speedup vs baseline: 1.4611x; 1.0403x over previous
//
#include <hip/hip_runtime.h>
#include <stdint.h>
#include <stdio.h>

typedef __attribute__((ext_vector_type(8))) short short8;
typedef __attribute__((ext_vector_type(4))) float f32x4;
typedef __attribute__((ext_vector_type(2))) float f32x2;
typedef __attribute__((ext_vector_type(4))) unsigned int u32x4;
typedef __attribute__((ext_vector_type(4))) unsigned short u16x4;

#define DEV static __device__ __forceinline__

DEV unsigned short f2bf(float f){
  unsigned u = __float_as_uint(f);
  u += 0x7FFFu + ((u >> 16) & 1u);          // RNE
  return (unsigned short)(u >> 16);
}
DEV float bf2f(unsigned short h){ return __uint_as_float(((unsigned)h) << 16); }

// ---------------------------------------------------------------------------
// zero ONLY the xt halo border pixels (rows {0,1,258,259} all cols; cols
// {0,1,258,259} rows 2..257).  Interior ch0-11 written by k_xt; ch12-15 never
// read by k_conv (stage decode ch = j%12, fragment reads cap at 11).
// 2064 border px/b x 256B.  grid 1032 x 256 thr x u32x4.
// ---------------------------------------------------------------------------
__global__ __launch_bounds__(256) void k_halo(unsigned short* __restrict__ xt){
  int tid = blockIdx.x * 256 + threadIdx.x;   // < 8*2064*16 = 264192
  int ch = tid & 15;
  int r = tid >> 4;                           // < 16512
  int k = r % 2064, b = r / 2064;
  int row, col;
  if (k < 1040){
    int rr = k / 260;                         // 0..3
    row = rr < 2 ? rr : 256 + rr;             // 0,1,258,259
    col = k % 260;
  } else {
    int k2 = k - 1040;
    row = 2 + (k2 >> 2);                      // 2..257
    int cc = k2 & 3;
    col = cc < 2 ? cc : 256 + cc;             // 0,1,258,259
  }
  u32x4 z = {0u, 0u, 0u, 0u};
  *(u32x4*)&xt[(((size_t)b * 260 + row) * 260 + col) * 128 + ch * 8] = z;
}

// ---------------------------------------------------------------------------
// x (8,96,256,256) f32  ->  xt (8,260,260,128) bf16 channels-last with halo=2
// ---------------------------------------------------------------------------
__global__ __launch_bounds__(256) void k_xt(const float* __restrict__ x,
                                            unsigned short* __restrict__ xt){
  int bid = blockIdx.x;                 // 8*256*4
  int wq = bid & 3, h = (bid >> 2) & 255, b = bid >> 10;
  int w0 = wq * 64;
  __shared__ unsigned short s[64 * 104];
  int t = threadIdx.x;
  int wl = t & 63, cq = t >> 6;         // cq 0..3
  const float* xp = x + ((size_t)b * 96 * 256 + h) * 256 + w0 + wl;
  #pragma unroll
  for (int i = 0; i < 24; ++i){
    int c = cq + i * 4;                 // 0..95
    s[wl * 104 + c] = f2bf(xp[(size_t)c * 65536]);
  }
  __syncthreads();
  unsigned short* dst = xt + (((size_t)b * 260 + h + 2) * 260 + (w0 + 2)) * 128;
  #pragma unroll
  for (int p = 0; p < 3; ++p){
    int i = t + p * 256;                // 0..767 = 64 w * 12 chunks
    int w = i / 12, ch = i % 12;
    u32x4 v = *(const u32x4*)&s[w * 104 + ch * 8];
    *(u32x4*)&dst[(size_t)w * 128 + ch * 8] = v;
  }
}

// ---------------------------------------------------------------------------
// weight repack (bf16):
//  A2  [768][ (kh*5+kw)*96 + ic ]   patch-conv weights (r then c)
//  Aun [m=co*4+p*2+q][ci 0..767]    unpatch weights
//  Agr [side][m 0..191][k 0..95]    gru weights transposed
//  bun [96] f32 = r_un_b + c_un_b
// ---------------------------------------------------------------------------
__global__ __launch_bounds__(256) void k_pack(const float* __restrict__ rpw, const float* __restrict__ cpw,
    const float* __restrict__ runw, const float* __restrict__ cunw,
    const float* __restrict__ runb, const float* __restrict__ cunb,
    const float* __restrict__ rgw,  const float* __restrict__ cgw,
    unsigned short* __restrict__ A2, unsigned short* __restrict__ Aun,
    unsigned short* __restrict__ Agr, float* __restrict__ bun){
  int tid = blockIdx.x * 256 + threadIdx.x;
  const int NA2 = 768 * 2400, NUN = 384 * 768, NGR = 2 * 192 * 96;
  if (tid < NA2){
    int oc = tid / 2400, r = tid % 2400;
    int kh = r / 480, kw = (r / 96) % 5, ic = r % 96;
    const float* W = oc < 384 ? rpw : cpw;
    int o = oc < 384 ? oc : oc - 384;
    A2[tid] = f2bf(W[(((size_t)o * 96 + ic) * 5 + kh) * 5 + kw]);
  } else if (tid < NA2 + NUN){
    int i = tid - NA2;
    int m = i / 768, ci = i % 768;
    int co = m >> 2, p = (m >> 1) & 1, q = m & 1;
    const float* W = ci < 384 ? runw : cunw;
    int c = ci < 384 ? ci : ci - 384;
    Aun[i] = f2bf(W[(((size_t)c * 96 + co) * 2 + p) * 2 + q]);
  } else if (tid < NA2 + NUN + NGR){
    int i = tid - NA2 - NUN;
    int side = i / 18432, r = i % 18432;
    int m = r / 96, k = r % 96;
    const float* W = side ? cgw : rgw;       // (96,192) row-major
    Agr[i] = f2bf(W[k * 192 + m]);
  } else if (tid < NA2 + NUN + NGR + 96){
    int co = tid - NA2 - NUN - NGR;
    bun[co] = runb[co] + cunb[co];
  }
}

// ---------------------------------------------------------------------------
// patch conv as implicit GEMM, v10 (validated round 16: 578 us, Mfma 37.6%).
// ---------------------------------------------------------------------------
__global__ __launch_bounds__(512) void k_conv(const unsigned short* __restrict__ xt,
    const unsigned short* __restrict__ A2,
    const float* __restrict__ rpb, const float* __restrict__ cpb,
    unsigned short* __restrict__ cl){
  __shared__ char lds[162240];
  const int ASZ = 26624;                // one A buffer [128][208B]
  const int BOFF = 53248;               // B region offset
  const int BPITCH = 27248;             // 131 cols * 208 B
  const int BITEMS = 6288;              // 4 rows * 131 cols * 12 ch
  int t = threadIdx.x, lane = t & 63;
  int wid = t >> 6, mw = wid >> 2, nw = wid & 3;
  int wl = lane & 15, cg = lane >> 4;
  int bid = blockIdx.x;                 // 3072 = 8 xcd * (64 pgrp * 6 m)
  int xcd = bid & 7, rr = bid >> 3;
  int mt = rr % 6, pgrp = rr / 6;
  int p = pgrp * 8 + xcd;               // pixel tile 0..511
  int wq = p & 1, hq = (p >> 1) & 31, b = p >> 6;
  int ho0 = hq * 4, wo0 = wq * 64;
  int M0 = mt * 128;

  int a_oc = t >> 2, a_q = t & 3;
  const unsigned short* Aoc = A2 + (size_t)(M0 + a_oc) * 2400 + a_q * 24;
  char* Adst = lds + a_oc * 208 + a_q * 48;

  f32x4 acc[4][4];
  #pragma unroll
  for (int i = 0; i < 4; ++i)
    #pragma unroll
    for (int j = 0; j < 4; ++j) acc[i][j] = (f32x4){0.f, 0.f, 0.f, 0.f};

  u32x4 aR[3], bR[13];
  #pragma unroll
  for (int c = 0; c < 3; ++c) aR[c] = *(const u32x4*)(Aoc + c * 8);
  #pragma unroll
  for (int it = 0; it < 13; ++it){
    int i = t + it * 512;
    if (i < BITEMS){
      int row = i / 1572, j = i % 1572, col = j / 12, ch = j % 12;
      bR[it] = *(const u32x4*)&xt[(((size_t)b * 260 + 2 * ho0 + 2 * row) * 260 + 2 * wo0 + col) * 128 + ch * 8];
    }
  }
  #pragma unroll
  for (int c = 0; c < 3; ++c) *(u32x4*)(Adst + c * 16) = aR[c];
  #pragma unroll
  for (int it = 0; it < 13; ++it){
    int i = t + it * 512;
    if (i < BITEMS){
      int row = i / 1572, j = i % 1572, col = j / 12, ch = j % 12;
      *(u32x4*)(lds + BOFF + row * BPITCH + col * 208 + ch * 16) = bR[it];
    }
  }
  __syncthreads();

  int cur = 0;
  for (int kh = 0; kh < 5; ++kh){
    #pragma unroll
    for (int kw = 0; kw < 5; ++kw){
      bool last = (kh == 4 && kw == 4);
      bool khb  = (kw == 4 && kh < 4);
      if (!last){
        int nkh = kh + (kw == 4 ? 1 : 0), nkw = (kw == 4 ? 0 : kw + 1);
        const unsigned short* As = Aoc + (nkh * 5 + nkw) * 96;
        #pragma unroll
        for (int c = 0; c < 3; ++c) aR[c] = *(const u32x4*)(As + c * 8);
      }
      if (khb){
        #pragma unroll
        for (int it = 0; it < 13; ++it){
          int i = t + it * 512;
          if (i < BITEMS){
            int row = i / 1572, j = i % 1572, col = j / 12, ch = j % 12;
            bR[it] = *(const u32x4*)&xt[(((size_t)b * 260 + 2 * ho0 + 2 * row + kh + 1) * 260 + 2 * wo0 + col) * 128 + ch * 8];
          }
        }
      }
      {
        char* Ab = lds + cur * ASZ;
        int col = 32 * nw + 2 * wl + kw;
        #pragma unroll
        for (int ics = 0; ics < 3; ++ics){
          short8 af[4], bfr[4];
          #pragma unroll
          for (int mf = 0; mf < 4; ++mf)
            af[mf] = *(const short8*)(Ab + (mw * 64 + mf * 16 + wl) * 208 + ics * 64 + cg * 16);
          #pragma unroll
          for (int nf = 0; nf < 4; ++nf)
            bfr[nf] = *(const short8*)(lds + BOFF + nf * BPITCH + col * 208 + (ics * 4 + cg) * 16);
          #pragma unroll
          for (int mf = 0; mf < 4; ++mf)
            #pragma unroll
            for (int nf = 0; nf < 4; ++nf)
              acc[mf][nf] = __builtin_amdgcn_mfma_f32_16x16x32_bf16(af[mf], bfr[nf], acc[mf][nf], 0, 0, 0);
        }
      }
      if (khb) __syncthreads();          // all waves done reading B(kh)
      if (!last){
        #pragma unroll
        for (int c = 0; c < 3; ++c) *(u32x4*)(Adst + (cur ^ 1) * ASZ + c * 16) = aR[c];
        if (khb){
          #pragma unroll
          for (int it = 0; it < 13; ++it){
            int i = t + it * 512;
            if (i < BITEMS){
              int row = i / 1572, j = i % 1572, col = j / 12, ch = j % 12;
              *(u32x4*)(lds + BOFF + row * BPITCH + col * 208 + ch * 16) = bR[it];
            }
          }
        }
        __syncthreads();                 // staged data visible
        cur ^= 1;
      }
    }
  }
  __syncthreads();                       // protect A/B reads before S overwrite
  unsigned short* S = (unsigned short*)lds;
  #pragma unroll
  for (int mf = 0; mf < 4; ++mf)
    #pragma unroll
    for (int nf = 0; nf < 4; ++nf){
      int wol = nw * 16 + wl;
      int pxl = nf * 64 + wol;
      int sw8 = (pxl & 7) << 3;
      #pragma unroll
      for (int j = 0; j < 4; ++j){
        int ocl = mw * 64 + mf * 16 + cg * 4 + j;
        int oc = M0 + ocl;
        float v = acc[mf][nf][j] + (oc < 384 ? rpb[oc] : cpb[oc - 384]);
        S[pxl * 128 + (ocl ^ sw8)] = f2bf(v);
      }
    }
  __syncthreads();
  #pragma unroll
  for (int it = 0; it < 8; ++it){
    int i = t + it * 512;               // 0..4095 = 256 px * 16 chunks
    int pxl = i >> 4, ch = i & 15;
    int chs = ch ^ (pxl & 7);
    int ho = ho0 + (pxl >> 6), wo = wo0 + (pxl & 63);
    u32x4 v = *(const u32x4*)&S[pxl * 128 + chs * 8];
    *(u32x4*)&cl[(((size_t)b * 128 + ho) * 128 + wo) * 768 + M0 + ch * 8] = v;
  }
}

// ---------------------------------------------------------------------------
// positional grouped conv 3x3, v2 (validated rounds 12-16).
// ---------------------------------------------------------------------------
__global__ __launch_bounds__(256) void k_pe(const unsigned short* __restrict__ cl,
    const float* __restrict__ rpew, const float* __restrict__ cpew,
    const float* __restrict__ rpeb, const float* __restrict__ cpeb,
    unsigned short* __restrict__ sum){
  __shared__ unsigned short si[340 * 52];  // [pix = r2*34+cc][ch pitch 52]
  __shared__ float sw[48 * 36];
  __shared__ float sb[48];
  int bid = blockIdx.x;                    // 8*16*16*4
  int wq = bid & 3, hq = (bid >> 2) & 15, slab = (bid >> 6) & 15, b = bid >> 10;
  int ch0 = slab * 48, hp0 = hq * 8, wp0 = wq * 32;
  int t = threadIdx.x;
  for (int i = t; i < 48 * 36; i += 256){
    int ocl = i / 36, r = i % 36;
    int oc = ch0 + ocl;
    const float* W = oc < 384 ? rpew : cpew;
    int o = oc < 384 ? oc : oc - 384;
    sw[i] = W[(size_t)o * 36 + r];
  }
  if (t < 48){
    int oc = ch0 + t;
    sb[t] = oc < 384 ? rpeb[oc] : cpeb[oc - 384];
  }
  for (int i = t; i < 340 * 24; i += 256){   // u32 = 2 ch at a time
    int pix = i / 24, c2 = i % 24;
    int r2 = pix / 34, cc = pix % 34;
    int hp = hp0 - 1 + r2, wp = wp0 - 1 + cc;
    unsigned v = 0;
    if (hp >= 0 && hp < 128 && wp >= 0 && wp < 128)
      v = *(const unsigned*)&cl[((size_t)b * 16384 + hp * 128 + wp) * 768 + ch0 + c2 * 2];
    *(unsigned*)&si[pix * 52 + c2 * 2] = v;
  }
  __syncthreads();
  int hpl = t >> 5, wpl = t & 31;
  unsigned int outp[24];
  #pragma unroll
  for (int g = 0; g < 12; ++g){
    float o0 = sb[g * 4], o1 = sb[g * 4 + 1], o2 = sb[g * 4 + 2], o3 = sb[g * 4 + 3];
    #pragma unroll
    for (int dh = 0; dh < 3; ++dh)
      #pragma unroll
      for (int dw = 0; dw < 3; ++dw){
        int pix = (hpl + dh) * 34 + (wpl + dw);
        u16x4 v = *(const u16x4*)&si[pix * 52 + g * 4];
        float x0 = bf2f(v[0]), x1 = bf2f(v[1]), x2 = bf2f(v[2]), x3 = bf2f(v[3]);
        int r = dh * 3 + dw;
        o0 = fmaf(sw[(g*4+0)*36 + 0*9 + r], x0, o0); o0 = fmaf(sw[(g*4+0)*36 + 1*9 + r], x1, o0);
        o0 = fmaf(sw[(g*4+0)*36 + 2*9 + r], x2, o0); o0 = fmaf(sw[(g*4+0)*36 + 3*9 + r], x3, o0);
        o1 = fmaf(sw[(g*4+1)*36 + 0*9 + r], x0, o1); o1 = fmaf(sw[(g*4+1)*36 + 1*9 + r], x1, o1);
        o1 = fmaf(sw[(g*4+1)*36 + 2*9 + r], x2, o1); o1 = fmaf(sw[(g*4+1)*36 + 3*9 + r], x3, o1);
        o2 = fmaf(sw[(g*4+2)*36 + 0*9 + r], x0, o2); o2 = fmaf(sw[(g*4+2)*36 + 1*9 + r], x1, o2);
        o2 = fmaf(sw[(g*4+2)*36 + 2*9 + r], x2, o2); o2 = fmaf(sw[(g*4+2)*36 + 3*9 + r], x3, o2);
        o3 = fmaf(sw[(g*4+3)*36 + 0*9 + r], x0, o3); o3 = fmaf(sw[(g*4+3)*36 + 1*9 + r], x1, o3);
        o3 = fmaf(sw[(g*4+3)*36 + 2*9 + r], x2, o3); o3 = fmaf(sw[(g*4+3)*36 + 3*9 + r], x3, o3);
      }
    outp[g * 2]     = (unsigned)f2bf(o0) | ((unsigned)f2bf(o1) << 16);
    outp[g * 2 + 1] = (unsigned)f2bf(o2) | ((unsigned)f2bf(o3) << 16);
  }
  size_t obase = (((size_t)b * 128 + hp0 + hpl) * 128 + wp0 + wpl) * 768 + ch0;
  #pragma unroll
  for (int c6 = 0; c6 < 6; ++c6){
    u32x4 v = { outp[c6 * 4], outp[c6 * 4 + 1], outp[c6 * 4 + 2], outp[c6 * 4 + 3] };
    *(u32x4*)&sum[obase + c6 * 8] = v;
  }
}

// ---------------------------------------------------------------------------
// FUSED hg-GEMM + minGRU scan, v2 with T14 (validated round 16).
// ---------------------------------------------------------------------------
__global__ __launch_bounds__(256) void k_gruf(const unsigned short* __restrict__ cl,
    const unsigned short* __restrict__ Agr, unsigned short* __restrict__ sum){
  __shared__ char lds[78848];
  const int AOFF = 0, BOFF2 = 39936, HOFF = 53248;
  int t = threadIdx.x, lane = t & 63, wid = t >> 6;
  int wl = lane & 15, cg = lane >> 4;
  int bid = blockIdx.x;
  int cb = bid & 7, head = (bid >> 3) & 3, b = (bid >> 5) & 7, side = bid >> 8;
  size_t clbase = ((size_t)b * 16384) * 768 + side * 384 + head * 96;
  for (int i = t; i < 2304; i += 256){
    int m = i / 12, c = i % 12;
    u32x4 v = *(const u32x4*)&Agr[((size_t)side * 192 + m) * 96 + c * 8];
    *(u32x4*)(lds + AOFF + m * 208 + c * 16) = v;
  }
  for (int i = t; i < 768; i += 256){
    int px = i / 12, c = i % 12;
    int s = px >> 4, xl = px & 15;
    int xg = cb * 16 + xl;
    int pxg = side ? (xg * 128 + s) : (s * 128 + xg);
    u32x4 v = *(const u32x4*)&cl[clbase + (size_t)pxg * 768 + c * 8];
    *(u32x4*)(lds + BOFF2 + px * 208 + c * 16) = v;
  }
  int s_chain = t & 15, s_dg = t >> 4;    // scan role: active if s_dg < 12
  float h[8];
  #pragma unroll
  for (int k = 0; k < 8; ++k) h[k] = 0.f;
  __syncthreads();

  for (int ch = 0; ch < 32; ++ch){
    int s0 = ch * 4;
    f32x4 acc[12];
    #pragma unroll
    for (int i = 0; i < 12; ++i) acc[i] = (f32x4){0.f, 0.f, 0.f, 0.f};
    #pragma unroll
    for (int ks = 0; ks < 3; ++ks){
      short8 bf = *(const short8*)(lds + BOFF2 + (wid * 16 + wl) * 208 + ks * 64 + cg * 16);
      #pragma unroll
      for (int mf = 0; mf < 12; ++mf){
        short8 af = *(const short8*)(lds + AOFF + (mf * 16 + wl) * 208 + ks * 64 + cg * 16);
        acc[mf] = __builtin_amdgcn_mfma_f32_16x16x32_bf16(af, bf, acc[mf], 0, 0, 0);
      }
    }
    {
      int px = wid * 16 + wl;
      #pragma unroll
      for (int mf = 0; mf < 12; ++mf){
        unsigned p0 = (unsigned)f2bf(acc[mf][0]) | ((unsigned)f2bf(acc[mf][1]) << 16);
        unsigned p1 = (unsigned)f2bf(acc[mf][2]) | ((unsigned)f2bf(acc[mf][3]) << 16);
        unsigned long long pp = (unsigned long long)p0 | ((unsigned long long)p1 << 32);
        *(unsigned long long*)(lds + HOFF + px * 400 + (mf * 16 + cg * 4) * 2) = pp;
      }
    }
    __syncthreads();
    u32x4 nb[3];
    if (ch < 31){
      int sn = (ch + 1) * 4;
      #pragma unroll
      for (int it = 0; it < 3; ++it){
        int i = t + it * 256;             // exactly 768 items
        int px = i / 12, c = i % 12;
        int s = px >> 4, xl = px & 15;
        int xg = cb * 16 + xl;
        int pxg = side ? (xg * 128 + (sn + s)) : ((sn + s) * 128 + xg);
        nb[it] = *(const u32x4*)&cl[clbase + (size_t)pxg * 768 + c * 8];
      }
    }
    if (s_dg < 12){
      #pragma unroll
      for (int s = 0; s < 4; ++s){
        int px = s * 16 + s_chain;
        short8 hid8 = *(const short8*)(lds + HOFF + px * 400 + s_dg * 16);
        short8 gat8 = *(const short8*)(lds + HOFF + px * 400 + 192 + s_dg * 16);
        int xg = cb * 16 + s_chain;
        int pxg = side ? (xg * 128 + (s0 + s)) : ((s0 + s) * 128 + xg);
        unsigned short* sp = (unsigned short*)&sum[clbase + (size_t)pxg * 768 + s_dg * 8];
        u32x4 sv = *(u32x4*)sp;
        unsigned short* svp = (unsigned short*)&sv;
        #pragma unroll
        for (int k = 0; k < 8; ++k){
          float hid = bf2f((unsigned short)hid8[k]);
          float gat = bf2f((unsigned short)gat8[k]);
          float z  = 1.f / (1.f + __expf(-gat));
          float th = hid >= 0.f ? hid + 0.5f : 1.f / (1.f + __expf(-hid));
          h[k] += z * (th - h[k]);
          svp[k] = f2bf(bf2f(svp[k]) + h[k]);
        }
        *(u32x4*)sp = sv;
      }
    }
    if (ch < 31){
      #pragma unroll
      for (int it = 0; it < 3; ++it){
        int i = t + it * 256;
        int px = i / 12, c = i % 12;
        *(u32x4*)(lds + BOFF2 + px * 208 + c * 16) = nb[it];
      }
    }
    __syncthreads();
  }
}

// ---------------------------------------------------------------------------
// unpatch, v4 = v3 + T14 async split: issue kc+1's A/B global loads into regs
// BEFORE the 48 MFMA of kc; ds_write after the read barrier.  Single LDS buf,
// same 2 barriers/kc; latency hides under MFMA.
// ---------------------------------------------------------------------------
__global__ __launch_bounds__(256) void k_unpatch(const unsigned short* __restrict__ sum,
    const unsigned short* __restrict__ Aun, const float* __restrict__ bun,
    float* __restrict__ out){
  __shared__ char lds[53248];            // A [128][208B] | B [128][208B]
  int t = threadIdx.x, lane = t & 63;
  int wid = t >> 6, mw = wid >> 1, nw = wid & 1;
  int bid = blockIdx.x;                  // 3072 = 8 xcd * (128 pgrp * 3 m)
  int xcd = bid & 7, rr = bid >> 3;
  int mt = rr % 3, pgrp = rr / 3;
  int M0 = mt * 128;
  size_t N0 = (size_t)(pgrp * 8 + xcd) * 128;
  f32x4 acc[4][4];
  #pragma unroll
  for (int i = 0; i < 4; ++i)
    #pragma unroll
    for (int j = 0; j < 4; ++j) acc[i][j] = (f32x4){0.f, 0.f, 0.f, 0.f};

  // decode for staging roles (6 items each of A and B per thread)
  int s_m = t / 2, s_c6 = (t & 1) * 6;   // A/B row = t/2, 6 chunks half
  const unsigned short* Arow = Aun + (size_t)(M0 + s_m) * 768 + s_c6 * 8;
  const unsigned short* Brow = sum + (N0 + s_m) * 768 + s_c6 * 8;
  char* Adst = lds + s_m * 208 + s_c6 * 16;
  char* Bdst = lds + 26624 + s_m * 208 + s_c6 * 16;

  u32x4 aRg[6], bRg[6];
  // prologue: stage kc=0 directly
  #pragma unroll
  for (int c = 0; c < 6; ++c){
    aRg[c] = *(const u32x4*)(Arow + c * 8);
    bRg[c] = *(const u32x4*)(Brow + c * 8);
  }
  #pragma unroll
  for (int c = 0; c < 6; ++c){
    *(u32x4*)(Adst + c * 16) = aRg[c];
    *(u32x4*)(Bdst + c * 16) = bRg[c];
  }
  __syncthreads();

  for (int kc = 0; kc < 8; ++kc){
    if (kc < 7){
      #pragma unroll
      for (int c = 0; c < 6; ++c){
        aRg[c] = *(const u32x4*)(Arow + (kc + 1) * 96 + c * 8);
        bRg[c] = *(const u32x4*)(Brow + (kc + 1) * 96 + c * 8);
      }
    }
    #pragma unroll
    for (int ks = 0; ks < 3; ++ks){
      short8 af[4], bfr[4];
      #pragma unroll
      for (int mf = 0; mf < 4; ++mf)
        af[mf] = *(const short8*)(lds + (mw * 64 + mf * 16 + (lane & 15)) * 208 + ks * 64 + (lane >> 4) * 16);
      #pragma unroll
      for (int nf = 0; nf < 4; ++nf)
        bfr[nf] = *(const short8*)(lds + 26624 + (nw * 64 + nf * 16 + (lane & 15)) * 208 + ks * 64 + (lane >> 4) * 16);
      #pragma unroll
      for (int mf = 0; mf < 4; ++mf)
        #pragma unroll
        for (int nf = 0; nf < 4; ++nf)
          acc[mf][nf] = __builtin_amdgcn_mfma_f32_16x16x32_bf16(af[mf], bfr[nf], acc[mf][nf], 0, 0, 0);
    }
    if (kc < 7){
      __syncthreads();                   // all waves done reading LDS[kc]
      #pragma unroll
      for (int c = 0; c < 6; ++c){
        *(u32x4*)(Adst + c * 16) = aRg[c];
        *(u32x4*)(Bdst + c * 16) = bRg[c];
      }
      __syncthreads();                   // kc+1 visible
    }
  }
  #pragma unroll
  for (int mf = 0; mf < 4; ++mf)
    #pragma unroll
    for (int nf = 0; nf < 4; ++nf){
      int m = M0 + mw * 64 + mf * 16 + (lane >> 4) * 4;   // multiple of 4
      int co = m >> 2;
      size_t px = N0 + nw * 64 + nf * 16 + (lane & 15);
      int b = (int)(px >> 14); int pxl = (int)(px & 16383);
      int hp = pxl >> 7, wp = pxl & 127;
      float bias = bun[co];
      f32x2 v01 = { acc[mf][nf][0] + bias, acc[mf][nf][1] + bias };
      f32x2 v23 = { acc[mf][nf][2] + bias, acc[mf][nf][3] + bias };
      size_t ob = (((size_t)b * 96 + co) * 256 + 2 * hp) * 256 + 2 * wp;
      *(f32x2*)&out[ob]       = v01;   // row 2hp,   cols 2wp..2wp+1 (q=0,1)
      *(f32x2*)&out[ob + 256] = v23;   // row 2hp+1
    }
}

// ---------------------------------------------------------------------------
extern "C" void kernel_launch(void* const* d_in, const int* in_sizes, int n_in,
                              void* d_out, int out_size, void* d_ws, size_t ws_size,
                              hipStream_t stream){
  (void)in_sizes; (void)n_in; (void)out_size;
  const float* x    = (const float*)d_in[0];
  const float* rpw  = (const float*)d_in[1];
  const float* rpb  = (const float*)d_in[2];
  const float* cpw  = (const float*)d_in[3];
  const float* cpb  = (const float*)d_in[4];
  const float* rpew = (const float*)d_in[5];
  const float* rpeb = (const float*)d_in[6];
  const float* cpew = (const float*)d_in[7];
  const float* cpeb = (const float*)d_in[8];
  const float* runw = (const float*)d_in[9];
  const float* runb = (const float*)d_in[10];
  const float* cunw = (const float*)d_in[11];
  const float* cunb = (const float*)d_in[12];
  const float* rgw  = (const float*)d_in[13];
  const float* cgw  = (const float*)d_in[14];

  char* ws = (char*)d_ws;
  const size_t SZ_XT   = (size_t)8 * 260 * 260 * 128 * 2;   // 138,444,800
  const size_t OFF_A2  = SZ_XT;
  const size_t SZ_A2   = (size_t)768 * 2400 * 2;
  const size_t OFF_AUN = OFF_A2 + SZ_A2;
  const size_t SZ_AUN  = (size_t)384 * 768 * 2;
  const size_t OFF_AGR = OFF_AUN + SZ_AUN;
  const size_t SZ_AGR  = (size_t)2 * 192 * 96 * 2;
  const size_t OFF_BUN = OFF_AGR + SZ_AGR;
  const size_t OFF_HG  = ((OFF_BUN + 384) + 255) & ~(size_t)255;
  const size_t SZ_PL   = (size_t)8 * 768 * 128 * 128 * 2;   // 201,326,592
  const size_t OFF_CL  = OFF_HG + SZ_PL;
  const size_t OFF_SUM = OFF_CL + SZ_PL;
  const size_t NEED    = OFF_SUM + SZ_PL;                   // ~747 MB
  if (ws_size < NEED){
    fprintf(stderr, "kernel_launch: ws_size %zu < needed %zu\n", ws_size, NEED);
    return;
  }
  unsigned short* xt  = (unsigned short*)(ws);
  unsigned short* A2  = (unsigned short*)(ws + OFF_A2);
  unsigned short* Aun = (unsigned short*)(ws + OFF_AUN);
  unsigned short* Agr = (unsigned short*)(ws + OFF_AGR);
  float*          bun = (float*)(ws + OFF_BUN);
  unsigned short* cl  = (unsigned short*)(ws + OFF_CL);
  unsigned short* sum = (unsigned short*)(ws + OFF_SUM);
  float* out = (float*)d_out;

  k_halo<<<dim3(1032),    dim3(256), 0, stream>>>(xt);
  k_xt  <<<dim3(8192),    dim3(256), 0, stream>>>(x, xt);
  k_pack<<<dim3(8497),    dim3(256), 0, stream>>>(rpw, cpw, runw, cunw, runb, cunb, rgw, cgw, A2, Aun, Agr, bun);
  k_conv<<<dim3(3072),    dim3(512), 0, stream>>>(xt, A2, rpb, cpb, cl);
  k_pe  <<<dim3(8192),    dim3(256), 0, stream>>>(cl, rpew, cpew, rpeb, cpeb, sum);
  k_gruf<<<dim3(512),     dim3(256), 0, stream>>>(cl, Agr, sum);
  k_unpatch<<<dim3(3072), dim3(256), 0, stream>>>(sum, Aun, bun, out);
}

// Round 18
// 1427.151 us; speedup vs baseline: 1.4620x; 1.0006x over previous
//
#include <hip/hip_runtime.h>
#include <stdint.h>
#include <stdio.h>

typedef __attribute__((ext_vector_type(8))) short short8;
typedef __attribute__((ext_vector_type(4))) float f32x4;
typedef __attribute__((ext_vector_type(2))) float f32x2;
typedef __attribute__((ext_vector_type(4))) unsigned int u32x4;
typedef __attribute__((ext_vector_type(4))) unsigned short u16x4;

#define DEV static __device__ __forceinline__

DEV unsigned short f2bf(float f){
  unsigned u = __float_as_uint(f);
  u += 0x7FFFu + ((u >> 16) & 1u);          // RNE
  return (unsigned short)(u >> 16);
}
DEV float bf2f(unsigned short h){ return __uint_as_float(((unsigned)h) << 16); }

// ---------------------------------------------------------------------------
// x (8,96,256,256) f32  ->  xt (8,260,260,128) bf16 channels-last with halo=2
// ---------------------------------------------------------------------------
__global__ __launch_bounds__(256) void k_xt(const float* __restrict__ x,
                                            unsigned short* __restrict__ xt){
  int bid = blockIdx.x;                 // 8*256*4
  int wq = bid & 3, h = (bid >> 2) & 255, b = bid >> 10;
  int w0 = wq * 64;
  __shared__ unsigned short s[64 * 104];
  int t = threadIdx.x;
  int wl = t & 63, cq = t >> 6;         // cq 0..3
  const float* xp = x + ((size_t)b * 96 * 256 + h) * 256 + w0 + wl;
  #pragma unroll
  for (int i = 0; i < 24; ++i){
    int c = cq + i * 4;                 // 0..95
    s[wl * 104 + c] = f2bf(xp[(size_t)c * 65536]);
  }
  __syncthreads();
  unsigned short* dst = xt + (((size_t)b * 260 + h + 2) * 260 + (w0 + 2)) * 128;
  #pragma unroll
  for (int p = 0; p < 3; ++p){
    int i = t + p * 256;                // 0..767 = 64 w * 12 chunks
    int w = i / 12, ch = i % 12;
    u32x4 v = *(const u32x4*)&s[w * 104 + ch * 8];
    *(u32x4*)&dst[(size_t)w * 128 + ch * 8] = v;
  }
}

// ---------------------------------------------------------------------------
// weight repack (bf16) + xt halo zeroing (merged, saves a launch):
//  A2  [768][ (kh*5+kw)*96 + ic ]   patch-conv weights (r then c)
//  Aun [m=co*4+p*2+q][ci 0..767]    unpatch weights
//  Agr [side][m 0..191][k 0..95]    gru weights transposed
//  bun [96] f32 = r_un_b + c_un_b
//  tail range: zero xt border px (rows {0,1,258,259} all cols; cols
//  {0,1,258,259} rows 2..257) x 16 chunks.  Interior ch12-15 never read.
// ---------------------------------------------------------------------------
__global__ __launch_bounds__(256) void k_pack(const float* __restrict__ rpw, const float* __restrict__ cpw,
    const float* __restrict__ runw, const float* __restrict__ cunw,
    const float* __restrict__ runb, const float* __restrict__ cunb,
    const float* __restrict__ rgw,  const float* __restrict__ cgw,
    unsigned short* __restrict__ A2, unsigned short* __restrict__ Aun,
    unsigned short* __restrict__ Agr, float* __restrict__ bun,
    unsigned short* __restrict__ xt){
  int tid = blockIdx.x * 256 + threadIdx.x;
  const int NA2 = 768 * 2400, NUN = 384 * 768, NGR = 2 * 192 * 96;
  const int NW = NA2 + NUN + NGR + 96;        // weights end
  if (tid < NA2){
    int oc = tid / 2400, r = tid % 2400;
    int kh = r / 480, kw = (r / 96) % 5, ic = r % 96;
    const float* W = oc < 384 ? rpw : cpw;
    int o = oc < 384 ? oc : oc - 384;
    A2[tid] = f2bf(W[(((size_t)o * 96 + ic) * 5 + kh) * 5 + kw]);
  } else if (tid < NA2 + NUN){
    int i = tid - NA2;
    int m = i / 768, ci = i % 768;
    int co = m >> 2, p = (m >> 1) & 1, q = m & 1;
    const float* W = ci < 384 ? runw : cunw;
    int c = ci < 384 ? ci : ci - 384;
    Aun[i] = f2bf(W[(((size_t)c * 96 + co) * 2 + p) * 2 + q]);
  } else if (tid < NA2 + NUN + NGR){
    int i = tid - NA2 - NUN;
    int side = i / 18432, r = i % 18432;
    int m = r / 96, k = r % 96;
    const float* W = side ? cgw : rgw;       // (96,192) row-major
    Agr[i] = f2bf(W[k * 192 + m]);
  } else if (tid < NW){
    int co = tid - NA2 - NUN - NGR;
    bun[co] = runb[co] + cunb[co];
  } else if (tid < NW + 264192){              // halo: 8*2064 border px * 16 ch
    int i = tid - NW;
    int ch = i & 15;
    int r = i >> 4;                           // < 16512
    int k = r % 2064, b = r / 2064;
    int row, col;
    if (k < 1040){
      int rr = k / 260;                       // 0..3
      row = rr < 2 ? rr : 256 + rr;           // 0,1,258,259
      col = k % 260;
    } else {
      int k2 = k - 1040;
      row = 2 + (k2 >> 2);                    // 2..257
      int cc = k2 & 3;
      col = cc < 2 ? cc : 256 + cc;           // 0,1,258,259
    }
    u32x4 z = {0u, 0u, 0u, 0u};
    *(u32x4*)&xt[(((size_t)b * 260 + row) * 260 + col) * 128 + ch * 8] = z;
  }
}

// ---------------------------------------------------------------------------
// patch conv as implicit GEMM, v11 = v10 + EARLY B-prefetch (issue at kw==1,
// 4 slabs of cover instead of 1; VGPR headroom 124/256 makes liveness free).
// 1D grid 3072 XCD-grouped.  512 threads = 8 waves (2mw x 4nw), block tile
// 128oc x 256px (4ho x 64wo), wave 64oc x 64px.
// LDS: A dbuf 2x[128][208B]=53248 | B [4r][131c][208B]=108992 -> 162240.
// ---------------------------------------------------------------------------
__global__ __launch_bounds__(512) void k_conv(const unsigned short* __restrict__ xt,
    const unsigned short* __restrict__ A2,
    const float* __restrict__ rpb, const float* __restrict__ cpb,
    unsigned short* __restrict__ cl){
  __shared__ char lds[162240];
  const int ASZ = 26624;                // one A buffer [128][208B]
  const int BOFF = 53248;               // B region offset
  const int BPITCH = 27248;             // 131 cols * 208 B
  const int BITEMS = 6288;              // 4 rows * 131 cols * 12 ch
  int t = threadIdx.x, lane = t & 63;
  int wid = t >> 6, mw = wid >> 2, nw = wid & 3;
  int wl = lane & 15, cg = lane >> 4;
  int bid = blockIdx.x;                 // 3072 = 8 xcd * (64 pgrp * 6 m)
  int xcd = bid & 7, rr = bid >> 3;
  int mt = rr % 6, pgrp = rr / 6;
  int p = pgrp * 8 + xcd;               // pixel tile 0..511
  int wq = p & 1, hq = (p >> 1) & 31, b = p >> 6;
  int ho0 = hq * 4, wo0 = wq * 64;
  int M0 = mt * 128;

  int a_oc = t >> 2, a_q = t & 3;
  const unsigned short* Aoc = A2 + (size_t)(M0 + a_oc) * 2400 + a_q * 24;
  char* Adst = lds + a_oc * 208 + a_q * 48;

  f32x4 acc[4][4];
  #pragma unroll
  for (int i = 0; i < 4; ++i)
    #pragma unroll
    for (int j = 0; j < 4; ++j) acc[i][j] = (f32x4){0.f, 0.f, 0.f, 0.f};

  u32x4 aR[3], bR[13];
  #pragma unroll
  for (int c = 0; c < 3; ++c) aR[c] = *(const u32x4*)(Aoc + c * 8);
  #pragma unroll
  for (int it = 0; it < 13; ++it){
    int i = t + it * 512;
    if (i < BITEMS){
      int row = i / 1572, j = i % 1572, col = j / 12, ch = j % 12;
      bR[it] = *(const u32x4*)&xt[(((size_t)b * 260 + 2 * ho0 + 2 * row) * 260 + 2 * wo0 + col) * 128 + ch * 8];
    }
  }
  #pragma unroll
  for (int c = 0; c < 3; ++c) *(u32x4*)(Adst + c * 16) = aR[c];
  #pragma unroll
  for (int it = 0; it < 13; ++it){
    int i = t + it * 512;
    if (i < BITEMS){
      int row = i / 1572, j = i % 1572, col = j / 12, ch = j % 12;
      *(u32x4*)(lds + BOFF + row * BPITCH + col * 208 + ch * 16) = bR[it];
    }
  }
  __syncthreads();

  int cur = 0;
  for (int kh = 0; kh < 5; ++kh){
    #pragma unroll
    for (int kw = 0; kw < 5; ++kw){
      bool last = (kh == 4 && kw == 4);
      bool khb_issue = (kw == 1 && kh < 4);   // EARLY issue: 4 slabs of cover
      bool khb_write = (kw == 4 && kh < 4);
      if (!last){
        int nkh = kh + (kw == 4 ? 1 : 0), nkw = (kw == 4 ? 0 : kw + 1);
        const unsigned short* As = Aoc + (nkh * 5 + nkw) * 96;
        #pragma unroll
        for (int c = 0; c < 3; ++c) aR[c] = *(const u32x4*)(As + c * 8);
      }
      if (khb_issue){
        #pragma unroll
        for (int it = 0; it < 13; ++it){
          int i = t + it * 512;
          if (i < BITEMS){
            int row = i / 1572, j = i % 1572, col = j / 12, ch = j % 12;
            bR[it] = *(const u32x4*)&xt[(((size_t)b * 260 + 2 * ho0 + 2 * row + kh + 1) * 260 + 2 * wo0 + col) * 128 + ch * 8];
          }
        }
      }
      {
        char* Ab = lds + cur * ASZ;
        int col = 32 * nw + 2 * wl + kw;
        #pragma unroll
        for (int ics = 0; ics < 3; ++ics){
          short8 af[4], bfr[4];
          #pragma unroll
          for (int mf = 0; mf < 4; ++mf)
            af[mf] = *(const short8*)(Ab + (mw * 64 + mf * 16 + wl) * 208 + ics * 64 + cg * 16);
          #pragma unroll
          for (int nf = 0; nf < 4; ++nf)
            bfr[nf] = *(const short8*)(lds + BOFF + nf * BPITCH + col * 208 + (ics * 4 + cg) * 16);
          #pragma unroll
          for (int mf = 0; mf < 4; ++mf)
            #pragma unroll
            for (int nf = 0; nf < 4; ++nf)
              acc[mf][nf] = __builtin_amdgcn_mfma_f32_16x16x32_bf16(af[mf], bfr[nf], acc[mf][nf], 0, 0, 0);
        }
      }
      if (khb_write) __syncthreads();    // all waves done reading B(kh)
      if (!last){
        #pragma unroll
        for (int c = 0; c < 3; ++c) *(u32x4*)(Adst + (cur ^ 1) * ASZ + c * 16) = aR[c];
        if (khb_write){
          #pragma unroll
          for (int it = 0; it < 13; ++it){
            int i = t + it * 512;
            if (i < BITEMS){
              int row = i / 1572, j = i % 1572, col = j / 12, ch = j % 12;
              *(u32x4*)(lds + BOFF + row * BPITCH + col * 208 + ch * 16) = bR[it];
            }
          }
        }
        __syncthreads();                 // staged data visible
        cur ^= 1;
      }
    }
  }
  __syncthreads();                       // protect A/B reads before S overwrite
  unsigned short* S = (unsigned short*)lds;
  #pragma unroll
  for (int mf = 0; mf < 4; ++mf)
    #pragma unroll
    for (int nf = 0; nf < 4; ++nf){
      int wol = nw * 16 + wl;
      int pxl = nf * 64 + wol;
      int sw8 = (pxl & 7) << 3;
      #pragma unroll
      for (int j = 0; j < 4; ++j){
        int ocl = mw * 64 + mf * 16 + cg * 4 + j;
        int oc = M0 + ocl;
        float v = acc[mf][nf][j] + (oc < 384 ? rpb[oc] : cpb[oc - 384]);
        S[pxl * 128 + (ocl ^ sw8)] = f2bf(v);
      }
    }
  __syncthreads();
  #pragma unroll
  for (int it = 0; it < 8; ++it){
    int i = t + it * 512;               // 0..4095 = 256 px * 16 chunks
    int pxl = i >> 4, ch = i & 15;
    int chs = ch ^ (pxl & 7);
    int ho = ho0 + (pxl >> 6), wo = wo0 + (pxl & 63);
    u32x4 v = *(const u32x4*)&S[pxl * 128 + chs * 8];
    *(u32x4*)&cl[(((size_t)b * 128 + ho) * 128 + wo) * 768 + M0 + ch * 8] = v;
  }
}

// ---------------------------------------------------------------------------
// positional grouped conv 3x3, v2 (validated rounds 12-17).
// ---------------------------------------------------------------------------
__global__ __launch_bounds__(256) void k_pe(const unsigned short* __restrict__ cl,
    const float* __restrict__ rpew, const float* __restrict__ cpew,
    const float* __restrict__ rpeb, const float* __restrict__ cpeb,
    unsigned short* __restrict__ sum){
  __shared__ unsigned short si[340 * 52];  // [pix = r2*34+cc][ch pitch 52]
  __shared__ float sw[48 * 36];
  __shared__ float sb[48];
  int bid = blockIdx.x;                    // 8*16*16*4
  int wq = bid & 3, hq = (bid >> 2) & 15, slab = (bid >> 6) & 15, b = bid >> 10;
  int ch0 = slab * 48, hp0 = hq * 8, wp0 = wq * 32;
  int t = threadIdx.x;
  for (int i = t; i < 48 * 36; i += 256){
    int ocl = i / 36, r = i % 36;
    int oc = ch0 + ocl;
    const float* W = oc < 384 ? rpew : cpew;
    int o = oc < 384 ? oc : oc - 384;
    sw[i] = W[(size_t)o * 36 + r];
  }
  if (t < 48){
    int oc = ch0 + t;
    sb[t] = oc < 384 ? rpeb[oc] : cpeb[oc - 384];
  }
  for (int i = t; i < 340 * 24; i += 256){   // u32 = 2 ch at a time
    int pix = i / 24, c2 = i % 24;
    int r2 = pix / 34, cc = pix % 34;
    int hp = hp0 - 1 + r2, wp = wp0 - 1 + cc;
    unsigned v = 0;
    if (hp >= 0 && hp < 128 && wp >= 0 && wp < 128)
      v = *(const unsigned*)&cl[((size_t)b * 16384 + hp * 128 + wp) * 768 + ch0 + c2 * 2];
    *(unsigned*)&si[pix * 52 + c2 * 2] = v;
  }
  __syncthreads();
  int hpl = t >> 5, wpl = t & 31;
  unsigned int outp[24];
  #pragma unroll
  for (int g = 0; g < 12; ++g){
    float o0 = sb[g * 4], o1 = sb[g * 4 + 1], o2 = sb[g * 4 + 2], o3 = sb[g * 4 + 3];
    #pragma unroll
    for (int dh = 0; dh < 3; ++dh)
      #pragma unroll
      for (int dw = 0; dw < 3; ++dw){
        int pix = (hpl + dh) * 34 + (wpl + dw);
        u16x4 v = *(const u16x4*)&si[pix * 52 + g * 4];
        float x0 = bf2f(v[0]), x1 = bf2f(v[1]), x2 = bf2f(v[2]), x3 = bf2f(v[3]);
        int r = dh * 3 + dw;
        o0 = fmaf(sw[(g*4+0)*36 + 0*9 + r], x0, o0); o0 = fmaf(sw[(g*4+0)*36 + 1*9 + r], x1, o0);
        o0 = fmaf(sw[(g*4+0)*36 + 2*9 + r], x2, o0); o0 = fmaf(sw[(g*4+0)*36 + 3*9 + r], x3, o0);
        o1 = fmaf(sw[(g*4+1)*36 + 0*9 + r], x0, o1); o1 = fmaf(sw[(g*4+1)*36 + 1*9 + r], x1, o1);
        o1 = fmaf(sw[(g*4+1)*36 + 2*9 + r], x2, o1); o1 = fmaf(sw[(g*4+1)*36 + 3*9 + r], x3, o1);
        o2 = fmaf(sw[(g*4+2)*36 + 0*9 + r], x0, o2); o2 = fmaf(sw[(g*4+2)*36 + 1*9 + r], x1, o2);
        o2 = fmaf(sw[(g*4+2)*36 + 2*9 + r], x2, o2); o2 = fmaf(sw[(g*4+2)*36 + 3*9 + r], x3, o2);
        o3 = fmaf(sw[(g*4+3)*36 + 0*9 + r], x0, o3); o3 = fmaf(sw[(g*4+3)*36 + 1*9 + r], x1, o3);
        o3 = fmaf(sw[(g*4+3)*36 + 2*9 + r], x2, o3); o3 = fmaf(sw[(g*4+3)*36 + 3*9 + r], x3, o3);
      }
    outp[g * 2]     = (unsigned)f2bf(o0) | ((unsigned)f2bf(o1) << 16);
    outp[g * 2 + 1] = (unsigned)f2bf(o2) | ((unsigned)f2bf(o3) << 16);
  }
  size_t obase = (((size_t)b * 128 + hp0 + hpl) * 128 + wp0 + wpl) * 768 + ch0;
  #pragma unroll
  for (int c6 = 0; c6 < 6; ++c6){
    u32x4 v = { outp[c6 * 4], outp[c6 * 4 + 1], outp[c6 * 4 + 2], outp[c6 * 4 + 3] };
    *(u32x4*)&sum[obase + c6 * 8] = v;
  }
}

// ---------------------------------------------------------------------------
// FUSED hg-GEMM + minGRU scan, v2 with T14 (validated rounds 16-17).
// ---------------------------------------------------------------------------
__global__ __launch_bounds__(256) void k_gruf(const unsigned short* __restrict__ cl,
    const unsigned short* __restrict__ Agr, unsigned short* __restrict__ sum){
  __shared__ char lds[78848];
  const int AOFF = 0, BOFF2 = 39936, HOFF = 53248;
  int t = threadIdx.x, lane = t & 63, wid = t >> 6;
  int wl = lane & 15, cg = lane >> 4;
  int bid = blockIdx.x;
  int cb = bid & 7, head = (bid >> 3) & 3, b = (bid >> 5) & 7, side = bid >> 8;
  size_t clbase = ((size_t)b * 16384) * 768 + side * 384 + head * 96;
  for (int i = t; i < 2304; i += 256){
    int m = i / 12, c = i % 12;
    u32x4 v = *(const u32x4*)&Agr[((size_t)side * 192 + m) * 96 + c * 8];
    *(u32x4*)(lds + AOFF + m * 208 + c * 16) = v;
  }
  for (int i = t; i < 768; i += 256){
    int px = i / 12, c = i % 12;
    int s = px >> 4, xl = px & 15;
    int xg = cb * 16 + xl;
    int pxg = side ? (xg * 128 + s) : (s * 128 + xg);
    u32x4 v = *(const u32x4*)&cl[clbase + (size_t)pxg * 768 + c * 8];
    *(u32x4*)(lds + BOFF2 + px * 208 + c * 16) = v;
  }
  int s_chain = t & 15, s_dg = t >> 4;    // scan role: active if s_dg < 12
  float h[8];
  #pragma unroll
  for (int k = 0; k < 8; ++k) h[k] = 0.f;
  __syncthreads();

  for (int ch = 0; ch < 32; ++ch){
    int s0 = ch * 4;
    f32x4 acc[12];
    #pragma unroll
    for (int i = 0; i < 12; ++i) acc[i] = (f32x4){0.f, 0.f, 0.f, 0.f};
    #pragma unroll
    for (int ks = 0; ks < 3; ++ks){
      short8 bf = *(const short8*)(lds + BOFF2 + (wid * 16 + wl) * 208 + ks * 64 + cg * 16);
      #pragma unroll
      for (int mf = 0; mf < 12; ++mf){
        short8 af = *(const short8*)(lds + AOFF + (mf * 16 + wl) * 208 + ks * 64 + cg * 16);
        acc[mf] = __builtin_amdgcn_mfma_f32_16x16x32_bf16(af, bf, acc[mf], 0, 0, 0);
      }
    }
    {
      int px = wid * 16 + wl;
      #pragma unroll
      for (int mf = 0; mf < 12; ++mf){
        unsigned p0 = (unsigned)f2bf(acc[mf][0]) | ((unsigned)f2bf(acc[mf][1]) << 16);
        unsigned p1 = (unsigned)f2bf(acc[mf][2]) | ((unsigned)f2bf(acc[mf][3]) << 16);
        unsigned long long pp = (unsigned long long)p0 | ((unsigned long long)p1 << 32);
        *(unsigned long long*)(lds + HOFF + px * 400 + (mf * 16 + cg * 4) * 2) = pp;
      }
    }
    __syncthreads();
    u32x4 nb[3];
    if (ch < 31){
      int sn = (ch + 1) * 4;
      #pragma unroll
      for (int it = 0; it < 3; ++it){
        int i = t + it * 256;             // exactly 768 items
        int px = i / 12, c = i % 12;
        int s = px >> 4, xl = px & 15;
        int xg = cb * 16 + xl;
        int pxg = side ? (xg * 128 + (sn + s)) : ((sn + s) * 128 + xg);
        nb[it] = *(const u32x4*)&cl[clbase + (size_t)pxg * 768 + c * 8];
      }
    }
    if (s_dg < 12){
      #pragma unroll
      for (int s = 0; s < 4; ++s){
        int px = s * 16 + s_chain;
        short8 hid8 = *(const short8*)(lds + HOFF + px * 400 + s_dg * 16);
        short8 gat8 = *(const short8*)(lds + HOFF + px * 400 + 192 + s_dg * 16);
        int xg = cb * 16 + s_chain;
        int pxg = side ? (xg * 128 + (s0 + s)) : ((s0 + s) * 128 + xg);
        unsigned short* sp = (unsigned short*)&sum[clbase + (size_t)pxg * 768 + s_dg * 8];
        u32x4 sv = *(u32x4*)sp;
        unsigned short* svp = (unsigned short*)&sv;
        #pragma unroll
        for (int k = 0; k < 8; ++k){
          float hid = bf2f((unsigned short)hid8[k]);
          float gat = bf2f((unsigned short)gat8[k]);
          float z  = 1.f / (1.f + __expf(-gat));
          float th = hid >= 0.f ? hid + 0.5f : 1.f / (1.f + __expf(-hid));
          h[k] += z * (th - h[k]);
          svp[k] = f2bf(bf2f(svp[k]) + h[k]);
        }
        *(u32x4*)sp = sv;
      }
    }
    if (ch < 31){
      #pragma unroll
      for (int it = 0; it < 3; ++it){
        int i = t + it * 256;
        int px = i / 12, c = i % 12;
        *(u32x4*)(lds + BOFF2 + px * 208 + c * 16) = nb[it];
      }
    }
    __syncthreads();
  }
}

// ---------------------------------------------------------------------------
// unpatch, v4 (validated round 17): T14 async split + XCD grid + f32x2 stores.
// ---------------------------------------------------------------------------
__global__ __launch_bounds__(256) void k_unpatch(const unsigned short* __restrict__ sum,
    const unsigned short* __restrict__ Aun, const float* __restrict__ bun,
    float* __restrict__ out){
  __shared__ char lds[53248];            // A [128][208B] | B [128][208B]
  int t = threadIdx.x, lane = t & 63;
  int wid = t >> 6, mw = wid >> 1, nw = wid & 1;
  int bid = blockIdx.x;                  // 3072 = 8 xcd * (128 pgrp * 3 m)
  int xcd = bid & 7, rr = bid >> 3;
  int mt = rr % 3, pgrp = rr / 3;
  int M0 = mt * 128;
  size_t N0 = (size_t)(pgrp * 8 + xcd) * 128;
  f32x4 acc[4][4];
  #pragma unroll
  for (int i = 0; i < 4; ++i)
    #pragma unroll
    for (int j = 0; j < 4; ++j) acc[i][j] = (f32x4){0.f, 0.f, 0.f, 0.f};

  int s_m = t / 2, s_c6 = (t & 1) * 6;   // A/B row = t/2, 6 chunks half
  const unsigned short* Arow = Aun + (size_t)(M0 + s_m) * 768 + s_c6 * 8;
  const unsigned short* Brow = sum + (N0 + s_m) * 768 + s_c6 * 8;
  char* Adst = lds + s_m * 208 + s_c6 * 16;
  char* Bdst = lds + 26624 + s_m * 208 + s_c6 * 16;

  u32x4 aRg[6], bRg[6];
  #pragma unroll
  for (int c = 0; c < 6; ++c){
    aRg[c] = *(const u32x4*)(Arow + c * 8);
    bRg[c] = *(const u32x4*)(Brow + c * 8);
  }
  #pragma unroll
  for (int c = 0; c < 6; ++c){
    *(u32x4*)(Adst + c * 16) = aRg[c];
    *(u32x4*)(Bdst + c * 16) = bRg[c];
  }
  __syncthreads();

  for (int kc = 0; kc < 8; ++kc){
    if (kc < 7){
      #pragma unroll
      for (int c = 0; c < 6; ++c){
        aRg[c] = *(const u32x4*)(Arow + (kc + 1) * 96 + c * 8);
        bRg[c] = *(const u32x4*)(Brow + (kc + 1) * 96 + c * 8);
      }
    }
    #pragma unroll
    for (int ks = 0; ks < 3; ++ks){
      short8 af[4], bfr[4];
      #pragma unroll
      for (int mf = 0; mf < 4; ++mf)
        af[mf] = *(const short8*)(lds + (mw * 64 + mf * 16 + (lane & 15)) * 208 + ks * 64 + (lane >> 4) * 16);
      #pragma unroll
      for (int nf = 0; nf < 4; ++nf)
        bfr[nf] = *(const short8*)(lds + 26624 + (nw * 64 + nf * 16 + (lane & 15)) * 208 + ks * 64 + (lane >> 4) * 16);
      #pragma unroll
      for (int mf = 0; mf < 4; ++mf)
        #pragma unroll
        for (int nf = 0; nf < 4; ++nf)
          acc[mf][nf] = __builtin_amdgcn_mfma_f32_16x16x32_bf16(af[mf], bfr[nf], acc[mf][nf], 0, 0, 0);
    }
    if (kc < 7){
      __syncthreads();                   // all waves done reading LDS[kc]
      #pragma unroll
      for (int c = 0; c < 6; ++c){
        *(u32x4*)(Adst + c * 16) = aRg[c];
        *(u32x4*)(Bdst + c * 16) = bRg[c];
      }
      __syncthreads();                   // kc+1 visible
    }
  }
  #pragma unroll
  for (int mf = 0; mf < 4; ++mf)
    #pragma unroll
    for (int nf = 0; nf < 4; ++nf){
      int m = M0 + mw * 64 + mf * 16 + (lane >> 4) * 4;   // multiple of 4
      int co = m >> 2;
      size_t px = N0 + nw * 64 + nf * 16 + (lane & 15);
      int b = (int)(px >> 14); int pxl = (int)(px & 16383);
      int hp = pxl >> 7, wp = pxl & 127;
      float bias = bun[co];
      f32x2 v01 = { acc[mf][nf][0] + bias, acc[mf][nf][1] + bias };
      f32x2 v23 = { acc[mf][nf][2] + bias, acc[mf][nf][3] + bias };
      size_t ob = (((size_t)b * 96 + co) * 256 + 2 * hp) * 256 + 2 * wp;
      *(f32x2*)&out[ob]       = v01;   // row 2hp,   cols 2wp..2wp+1 (q=0,1)
      *(f32x2*)&out[ob + 256] = v23;   // row 2hp+1
    }
}

// ---------------------------------------------------------------------------
extern "C" void kernel_launch(void* const* d_in, const int* in_sizes, int n_in,
                              void* d_out, int out_size, void* d_ws, size_t ws_size,
                              hipStream_t stream){
  (void)in_sizes; (void)n_in; (void)out_size;
  const float* x    = (const float*)d_in[0];
  const float* rpw  = (const float*)d_in[1];
  const float* rpb  = (const float*)d_in[2];
  const float* cpw  = (const float*)d_in[3];
  const float* cpb  = (const float*)d_in[4];
  const float* rpew = (const float*)d_in[5];
  const float* rpeb = (const float*)d_in[6];
  const float* cpew = (const float*)d_in[7];
  const float* cpeb = (const float*)d_in[8];
  const float* runw = (const float*)d_in[9];
  const float* runb = (const float*)d_in[10];
  const float* cunw = (const float*)d_in[11];
  const float* cunb = (const float*)d_in[12];
  const float* rgw  = (const float*)d_in[13];
  const float* cgw  = (const float*)d_in[14];

  char* ws = (char*)d_ws;
  const size_t SZ_XT   = (size_t)8 * 260 * 260 * 128 * 2;   // 138,444,800
  const size_t OFF_A2  = SZ_XT;
  const size_t SZ_A2   = (size_t)768 * 2400 * 2;
  const size_t OFF_AUN = OFF_A2 + SZ_A2;
  const size_t SZ_AUN  = (size_t)384 * 768 * 2;
  const size_t OFF_AGR = OFF_AUN + SZ_AUN;
  const size_t SZ_AGR  = (size_t)2 * 192 * 96 * 2;
  const size_t OFF_BUN = OFF_AGR + SZ_AGR;
  const size_t OFF_HG  = ((OFF_BUN + 384) + 255) & ~(size_t)255;
  const size_t SZ_PL   = (size_t)8 * 768 * 128 * 128 * 2;   // 201,326,592
  const size_t OFF_CL  = OFF_HG + SZ_PL;
  const size_t OFF_SUM = OFF_CL + SZ_PL;
  const size_t NEED    = OFF_SUM + SZ_PL;                   // ~747 MB
  if (ws_size < NEED){
    fprintf(stderr, "kernel_launch: ws_size %zu < needed %zu\n", ws_size, NEED);
    return;
  }
  unsigned short* xt  = (unsigned short*)(ws);
  unsigned short* A2  = (unsigned short*)(ws + OFF_A2);
  unsigned short* Aun = (unsigned short*)(ws + OFF_AUN);
  unsigned short* Agr = (unsigned short*)(ws + OFF_AGR);
  float*          bun = (float*)(ws + OFF_BUN);
  unsigned short* cl  = (unsigned short*)(ws + OFF_CL);
  unsigned short* sum = (unsigned short*)(ws + OFF_SUM);
  float* out = (float*)d_out;

  k_xt  <<<dim3(8192),    dim3(256), 0, stream>>>(x, xt);
  k_pack<<<dim3(10529),   dim3(256), 0, stream>>>(rpw, cpw, runw, cunw, runb, cunb, rgw, cgw, A2, Aun, Agr, bun, xt);
  k_conv<<<dim3(3072),    dim3(512), 0, stream>>>(xt, A2, rpb, cpb, cl);
  k_pe  <<<dim3(8192),    dim3(256), 0, stream>>>(cl, rpew, cpew, rpeb, cpeb, sum);
  k_gruf<<<dim3(512),     dim3(256), 0, stream>>>(cl, Agr, sum);
  k_unpatch<<<dim3(3072), dim3(256), 0, stream>>>(sum, Aun, bun, out);
}